// Round 1
// baseline (4878.820 us; speedup 1.0000x reference)
//
#include <hip/hip_runtime.h>

#define CDIV(a,b) (((a)+(b)-1)/(b))

// ---- ordered-uint encoding for float atomicMax ----
__device__ __forceinline__ unsigned fenc(float f) {
  unsigned u = __float_as_uint(f);
  return (u & 0x80000000u) ? ~u : (u | 0x80000000u);
}
__device__ __forceinline__ float fdec(unsigned e) {
  unsigned u = (e & 0x80000000u) ? (e & 0x7FFFFFFFu) : ~e;
  return __uint_as_float(u);
}

// ---------------- GEMM: Y[n, NOUT] = X[n,128] @ W[128, NOUT] ----------------
template<int NOUT>
__global__ __launch_bounds__(256) void gemm_k128(const float* __restrict__ X,
                                                 const float* __restrict__ W,
                                                 float* __restrict__ Y, int nrows) {
  constexpr int K = 128;
  constexpr int TPR = NOUT / 4;      // threads per row (32 for 128, 16 for 64)
  constexpr int RPB = 256 / TPR;     // rows per block-iter (8 or 16)
  __shared__ float Ws[K * NOUT];
  __shared__ float Xs[RPB][K];
  for (int i = threadIdx.x; i < K * NOUT; i += 256) Ws[i] = W[i];
  const int rg = threadIdx.x / TPR;
  const int cg = threadIdx.x % TPR;
  const int c0 = cg * 4;
  for (int base = blockIdx.x * RPB; base < nrows; base += gridDim.x * RPB) {
    __syncthreads();   // first iter: covers Ws staging; later: protects Xs reuse
    for (int i = threadIdx.x; i < RPB * K; i += 256) {
      int r = i >> 7, k = i & 127;
      int row = base + r;
      Xs[r][k] = (row < nrows) ? X[(size_t)row * K + k] : 0.f;
    }
    __syncthreads();
    int row = base + rg;
    if (row < nrows) {
      float a0 = 0.f, a1 = 0.f, a2 = 0.f, a3 = 0.f;
      #pragma unroll 4
      for (int k = 0; k < K; ++k) {
        float xv = Xs[rg][k];
        float4 w = *reinterpret_cast<const float4*>(&Ws[k * NOUT + c0]);
        a0 += xv * w.x; a1 += xv * w.y; a2 += xv * w.z; a3 += xv * w.w;
      }
      float4 o = make_float4(a0, a1, a2, a3);
      *reinterpret_cast<float4*>(&Y[(size_t)row * NOUT + c0]) = o;
    }
  }
}

// --------- per-node attention scores: s_src/s_dst[n,h] = <h[n,h,:], a_{s,d}[h,:]> ---------
template<int HEADS, int CH>
__global__ __launch_bounds__(256) void scores_kernel(const float* __restrict__ Hf,
                                                     const float* __restrict__ as_,
                                                     const float* __restrict__ ad_,
                                                     float* __restrict__ ssrc,
                                                     float* __restrict__ sdst, int n) {
  int t = blockIdx.x * blockDim.x + threadIdx.x;
  if (t >= n * HEADS) return;
  int hd = t % HEADS;
  const float* hp = Hf + (size_t)t * CH;   // t == node*HEADS + hd, rows contiguous
  float a = 0.f, b = 0.f;
  #pragma unroll
  for (int c = 0; c < CH; ++c) {
    float v = hp[c];
    a += v * as_[hd * CH + c];
    b += v * ad_[hd * CH + c];
  }
  ssrc[t] = a; sdst[t] = b;
}

// --------- edge pass 1: segment max of leaky_relu(s_src[src]+s_dst[dst]) over dst ---------
template<int HEADS>
__global__ __launch_bounds__(256) void edge_max_kernel(const int* __restrict__ ei, int E, int N,
                                                       const float* __restrict__ ssrc,
                                                       const float* __restrict__ sdst,
                                                       unsigned* __restrict__ m) {
  int e = blockIdx.x * blockDim.x + threadIdx.x;
  if (e >= E + N) return;
  int s, d;
  if (e < E) { s = ei[e]; d = ei[E + e]; } else { s = d = e - E; }
  #pragma unroll
  for (int h = 0; h < HEADS; ++h) {
    float v = ssrc[s * HEADS + h] + sdst[d * HEADS + h];
    v = v > 0.f ? v : 0.2f * v;
    atomicMax(&m[d * HEADS + h], fenc(v));
  }
}

// --------- edge pass 2: denominator sum of exp(logit - max) ---------
template<int HEADS>
__global__ __launch_bounds__(256) void edge_den_kernel(const int* __restrict__ ei, int E, int N,
                                                       const float* __restrict__ ssrc,
                                                       const float* __restrict__ sdst,
                                                       const unsigned* __restrict__ m,
                                                       float* __restrict__ den) {
  int e = blockIdx.x * blockDim.x + threadIdx.x;
  if (e >= E + N) return;
  int s, d;
  if (e < E) { s = ei[e]; d = ei[E + e]; } else { s = d = e - E; }
  #pragma unroll
  for (int h = 0; h < HEADS; ++h) {
    float v = ssrc[s * HEADS + h] + sdst[d * HEADS + h];
    v = v > 0.f ? v : 0.2f * v;
    float ex = __expf(v - fdec(m[d * HEADS + h]));
    atomicAdd(&den[d * HEADS + h], ex);
  }
}

// --------- edge pass 3: out[dst] += h[src] * alpha  (one wave per edge) ---------
template<int HEADS, int CH, int VEC>   // NOUT = HEADS*CH; VEC = NOUT/64
__global__ __launch_bounds__(256) void edge_aggr_kernel(const int* __restrict__ ei, int E, int N,
                                                        const float* __restrict__ Hf,
                                                        const float* __restrict__ ssrc,
                                                        const float* __restrict__ sdst,
                                                        const unsigned* __restrict__ m,
                                                        const float* __restrict__ den,
                                                        float* __restrict__ out) {
  constexpr int NOUT = HEADS * CH;
  long long gt = (long long)blockIdx.x * blockDim.x + threadIdx.x;
  int e = (int)(gt >> 6);
  int lane = (int)(gt & 63);
  if (e >= E + N) return;
  int s, d;
  if (e < E) { s = ei[e]; d = ei[E + e]; } else { s = d = e - E; }
  int c0 = lane * VEC;
  int h = c0 / CH;
  float v = ssrc[s * HEADS + h] + sdst[d * HEADS + h];
  v = v > 0.f ? v : 0.2f * v;
  float alpha = __expf(v - fdec(m[d * HEADS + h])) / den[d * HEADS + h];
  if (VEC == 2) {
    float2 hv = *reinterpret_cast<const float2*>(&Hf[(size_t)s * NOUT + c0]);
    atomicAdd(&out[(size_t)d * NOUT + c0], hv.x * alpha);
    atomicAdd(&out[(size_t)d * NOUT + c0 + 1], hv.y * alpha);
  } else {
    float hv = Hf[(size_t)s * NOUT + c0];
    atomicAdd(&out[(size_t)d * NOUT + c0], hv * alpha);
  }
}

// --------- bias + BatchNorm(eval) + ELU, in place ---------
__global__ __launch_bounds__(256) void post_kernel(float* __restrict__ buf,
                                                   const float* __restrict__ b,
                                                   const float* __restrict__ g,
                                                   const float* __restrict__ be,
                                                   const float* __restrict__ rm,
                                                   const float* __restrict__ rv,
                                                   int total, int nc) {
  int t = blockIdx.x * blockDim.x + threadIdx.x;
  if (t >= total) return;
  int c = t & (nc - 1);   // nc is a power of 2 (128)
  float x = buf[t] + b[c];
  float y = (x - rm[c]) * rsqrtf(rv[c] + 1e-5f) * g[c] + be[c];
  buf[t] = y > 0.f ? y : expm1f(y);
}

// --------- final bias add, in place on d_out ---------
__global__ __launch_bounds__(256) void bias_kernel(float* __restrict__ out,
                                                   const float* __restrict__ b,
                                                   int total, int nc) {
  int t = blockIdx.x * blockDim.x + threadIdx.x;
  if (t >= total) return;
  out[t] += b[t & (nc - 1)];
}

extern "C" void kernel_launch(void* const* d_in, const int* in_sizes, int n_in,
                              void* d_out, int out_size, void* d_ws, size_t ws_size,
                              hipStream_t stream) {
  const float* x   = (const float*)d_in[0];
  const int*   ei  = (const int*)d_in[1];
  const float* W1  = (const float*)d_in[2];
  const float* as1 = (const float*)d_in[3];
  const float* ad1 = (const float*)d_in[4];
  const float* b1  = (const float*)d_in[5];
  const float* g1  = (const float*)d_in[6];
  const float* be1 = (const float*)d_in[7];
  const float* rm1 = (const float*)d_in[8];
  const float* rv1 = (const float*)d_in[9];
  const float* W2  = (const float*)d_in[10];
  const float* as2 = (const float*)d_in[11];
  const float* ad2 = (const float*)d_in[12];
  const float* b2  = (const float*)d_in[13];
  const float* g2  = (const float*)d_in[14];
  const float* be2 = (const float*)d_in[15];
  const float* rm2 = (const float*)d_in[16];
  const float* rv2 = (const float*)d_in[17];
  const float* W3  = (const float*)d_in[18];
  const float* as3 = (const float*)d_in[19];
  const float* ad3 = (const float*)d_in[20];
  const float* b3  = (const float*)d_in[21];

  const int N  = in_sizes[0] / 128;
  const int E  = in_sizes[1] / 2;
  const int ET = E + N;
  float* out = (float*)d_out;

  // workspace layout
  float*    A    = (float*)d_ws;                 // N*128
  float*    B    = A + (size_t)N * 128;          // N*128
  float*    ssrc = B + (size_t)N * 128;          // N*4
  float*    sdst = ssrc + (size_t)N * 4;         // N*4
  unsigned* mbuf = (unsigned*)(sdst + (size_t)N * 4); // N*4
  float*    den  = (float*)(mbuf + (size_t)N * 4);    // N*4

  const int GB = 2048;                  // GEMM grid
  const int eb = CDIV(ET, 256);         // per-edge grid
  const int ab128 = CDIV((long long)ET * 64, 256); // wave-per-edge grid

  // ---------------- layer 1: GAT(128 -> 4x32) + BN + ELU ----------------
  gemm_k128<128><<<GB, 256, 0, stream>>>(x, W1, A, N);
  scores_kernel<4, 32><<<CDIV(N * 4, 256), 256, 0, stream>>>(A, as1, ad1, ssrc, sdst, N);
  hipMemsetAsync(mbuf, 0, (size_t)N * 4 * sizeof(unsigned), stream);
  hipMemsetAsync(den,  0, (size_t)N * 4 * sizeof(float), stream);
  edge_max_kernel<4><<<eb, 256, 0, stream>>>(ei, E, N, ssrc, sdst, mbuf);
  edge_den_kernel<4><<<eb, 256, 0, stream>>>(ei, E, N, ssrc, sdst, mbuf, den);
  hipMemsetAsync(B, 0, (size_t)N * 128 * sizeof(float), stream);
  edge_aggr_kernel<4, 32, 2><<<ab128, 256, 0, stream>>>(ei, E, N, A, ssrc, sdst, mbuf, den, B);
  post_kernel<<<CDIV(N * 128, 256), 256, 0, stream>>>(B, b1, g1, be1, rm1, rv1, N * 128, 128);

  // ---------------- layer 2: GAT(128 -> 4x32) + BN + ELU ----------------
  gemm_k128<128><<<GB, 256, 0, stream>>>(B, W2, A, N);
  scores_kernel<4, 32><<<CDIV(N * 4, 256), 256, 0, stream>>>(A, as2, ad2, ssrc, sdst, N);
  hipMemsetAsync(mbuf, 0, (size_t)N * 4 * sizeof(unsigned), stream);
  hipMemsetAsync(den,  0, (size_t)N * 4 * sizeof(float), stream);
  edge_max_kernel<4><<<eb, 256, 0, stream>>>(ei, E, N, ssrc, sdst, mbuf);
  edge_den_kernel<4><<<eb, 256, 0, stream>>>(ei, E, N, ssrc, sdst, mbuf, den);
  hipMemsetAsync(B, 0, (size_t)N * 128 * sizeof(float), stream);
  edge_aggr_kernel<4, 32, 2><<<ab128, 256, 0, stream>>>(ei, E, N, A, ssrc, sdst, mbuf, den, B);
  post_kernel<<<CDIV(N * 128, 256), 256, 0, stream>>>(B, b2, g2, be2, rm2, rv2, N * 128, 128);

  // ---------------- layer 3: GAT(128 -> 64, heads=1) ----------------
  gemm_k128<64><<<GB, 256, 0, stream>>>(B, W3, A, N);
  scores_kernel<1, 64><<<CDIV(N, 256), 256, 0, stream>>>(A, as3, ad3, ssrc, sdst, N);
  hipMemsetAsync(mbuf, 0, (size_t)N * sizeof(unsigned), stream);
  hipMemsetAsync(den,  0, (size_t)N * sizeof(float), stream);
  edge_max_kernel<1><<<eb, 256, 0, stream>>>(ei, E, N, ssrc, sdst, mbuf);
  edge_den_kernel<1><<<eb, 256, 0, stream>>>(ei, E, N, ssrc, sdst, mbuf, den);
  hipMemsetAsync(out, 0, (size_t)N * 64 * sizeof(float), stream);
  edge_aggr_kernel<1, 64, 1><<<ab128, 256, 0, stream>>>(ei, E, N, A, ssrc, sdst, mbuf, den, out);
  bias_kernel<<<CDIV(N * 64, 256), 256, 0, stream>>>(out, b3, N * 64, 64);
}

// Round 2
// 1275.535 us; speedup vs baseline: 3.8249x; 3.8249x over previous
//
#include <hip/hip_runtime.h>

#define CDIV(a,b) (((a)+(b)-1)/(b))

// ---------------- GEMM: Y[n, NOUT] = X[n,128] @ W[128, NOUT] ----------------
template<int NOUT>
__global__ __launch_bounds__(256) void gemm_k128(const float* __restrict__ X,
                                                 const float* __restrict__ W,
                                                 float* __restrict__ Y, int nrows) {
  constexpr int K = 128;
  constexpr int TPR = NOUT / 4;      // threads per row (32 for 128, 16 for 64)
  constexpr int RPB = 256 / TPR;     // rows per block-iter (8 or 16)
  __shared__ float Ws[K * NOUT];
  __shared__ float Xs[RPB][K];
  for (int i = threadIdx.x; i < K * NOUT; i += 256) Ws[i] = W[i];
  const int rg = threadIdx.x / TPR;
  const int cg = threadIdx.x % TPR;
  const int c0 = cg * 4;
  for (int base = blockIdx.x * RPB; base < nrows; base += gridDim.x * RPB) {
    __syncthreads();   // first iter: covers Ws staging; later: protects Xs reuse
    for (int i = threadIdx.x; i < RPB * K; i += 256) {
      int r = i >> 7, k = i & 127;
      int row = base + r;
      Xs[r][k] = (row < nrows) ? X[(size_t)row * K + k] : 0.f;
    }
    __syncthreads();
    int row = base + rg;
    if (row < nrows) {
      float a0 = 0.f, a1 = 0.f, a2 = 0.f, a3 = 0.f;
      #pragma unroll 4
      for (int k = 0; k < K; ++k) {
        float xv = Xs[rg][k];
        float4 w = *reinterpret_cast<const float4*>(&Ws[k * NOUT + c0]);
        a0 += xv * w.x; a1 += xv * w.y; a2 += xv * w.z; a3 += xv * w.w;
      }
      float4 o = make_float4(a0, a1, a2, a3);
      *reinterpret_cast<float4*>(&Y[(size_t)row * NOUT + c0]) = o;
    }
  }
}

// --------- per-node attention scores: s_src/s_dst[n,h] = <h[n,h,:], a_{s,d}[h,:]> ---------
template<int HEADS, int CH>
__global__ __launch_bounds__(256) void scores_kernel(const float* __restrict__ Hf,
                                                     const float* __restrict__ as_,
                                                     const float* __restrict__ ad_,
                                                     float* __restrict__ ssrc,
                                                     float* __restrict__ sdst, int n) {
  int t = blockIdx.x * blockDim.x + threadIdx.x;
  if (t >= n * HEADS) return;
  int hd = t % HEADS;
  const float* hp = Hf + (size_t)t * CH;   // t == node*HEADS + hd, rows contiguous
  float a = 0.f, b = 0.f;
  #pragma unroll
  for (int c = 0; c < CH; ++c) {
    float v = hp[c];
    a += v * as_[hd * CH + c];
    b += v * ad_[hd * CH + c];
  }
  ssrc[t] = a; sdst[t] = b;
}

// ---------------- CSR build: histogram of dst ----------------
__global__ __launch_bounds__(256) void hist_kernel(const int* __restrict__ ei, int E,
                                                   int* __restrict__ deg) {
  int e = blockIdx.x * blockDim.x + threadIdx.x;
  if (e >= E) return;
  atomicAdd(&deg[ei[E + e]], 1);
}

// ---------------- CSR build: one-block exclusive scan (N ~ 100K) ----------------
__global__ __launch_bounds__(1024) void scan_kernel(const int* __restrict__ deg,
                                                    int* __restrict__ rowptr,
                                                    int* __restrict__ cursor, int N) {
  __shared__ int part[1024];
  const int t = threadIdx.x;
  const int chunk = CDIV(N, 1024);
  const int lo = t * chunk;
  const int hi = min(lo + chunk, N);
  int s = 0;
  for (int i = lo; i < hi; ++i) s += deg[i];
  part[t] = s;
  __syncthreads();
  // inclusive Hillis-Steele scan over part[]
  for (int off = 1; off < 1024; off <<= 1) {
    int tmp = (t >= off) ? part[t - off] : 0;
    __syncthreads();
    part[t] += tmp;
    __syncthreads();
  }
  int run = part[t] - s;    // exclusive prefix for this thread's chunk
  for (int i = lo; i < hi; ++i) {
    int d = deg[i];
    rowptr[i] = run;
    cursor[i] = run;
    run += d;
  }
  if (t == 1023) rowptr[N] = part[1023];
}

// ---------------- CSR build: scatter src ids into per-dst buckets ----------------
__global__ __launch_bounds__(256) void scatter_kernel(const int* __restrict__ ei, int E,
                                                      int* __restrict__ cursor,
                                                      int* __restrict__ col) {
  int e = blockIdx.x * blockDim.x + threadIdx.x;
  if (e >= E) return;
  int d = ei[E + e];
  int pos = atomicAdd(&cursor[d], 1);
  col[pos] = ei[e];
}

// --------- fused GAT aggregation: one wave per node, online softmax over CSR ---------
// out[n,:] = epilogue( sum_{e->n} alpha_e * h[src_e,:] )
template<int HEADS, int CH, int VEC, bool BN>   // NOUT = HEADS*CH; VEC = NOUT/64
__global__ __launch_bounds__(256) void gat_aggr_csr(
    const int* __restrict__ rowptr, const int* __restrict__ col,
    const float* __restrict__ Hf,
    const float* __restrict__ ssrc, const float* __restrict__ sdst,
    const float* __restrict__ bias, const float* __restrict__ g,
    const float* __restrict__ be, const float* __restrict__ rm,
    const float* __restrict__ rv,
    float* __restrict__ out, int N) {
  constexpr int NOUT = HEADS * CH;
  const int wid = blockIdx.x * 4 + (threadIdx.x >> 6);
  const int lane = threadIdx.x & 63;
  if (wid >= N) return;
  const int n = wid;
  const int c0 = lane * VEC;
  const int head = c0 / CH;
  const float sd = sdst[n * HEADS + head];

  // self loop first (guarantees denominator > 0)
  float l = ssrc[n * HEADS + head] + sd;
  l = l > 0.f ? l : 0.2f * l;
  float m = l, s = 1.f;
  float a0 = Hf[(size_t)n * NOUT + c0];
  float a1 = (VEC == 2) ? Hf[(size_t)n * NOUT + c0 + 1] : 0.f;

  const int beg = rowptr[n], end = rowptr[n + 1];
  for (int e = beg; e < end; ++e) {
    int src = col[e];
    float lg = ssrc[src * HEADS + head] + sd;
    lg = lg > 0.f ? lg : 0.2f * lg;
    float nm = fmaxf(m, lg);
    float r = __expf(m - nm);
    float p = __expf(lg - nm);
    float h0 = Hf[(size_t)src * NOUT + c0];
    float h1 = (VEC == 2) ? Hf[(size_t)src * NOUT + c0 + 1] : 0.f;
    a0 = a0 * r + p * h0;
    a1 = a1 * r + p * h1;
    s = s * r + p;
    m = nm;
  }
  const float inv = 1.f / s;

  float o0 = a0 * inv + bias[c0];
  if (BN) {
    o0 = (o0 - rm[c0]) * rsqrtf(rv[c0] + 1e-5f) * g[c0] + be[c0];
    o0 = o0 > 0.f ? o0 : expm1f(o0);
  }
  if (VEC == 2) {
    float o1 = a1 * inv + bias[c0 + 1];
    if (BN) {
      o1 = (o1 - rm[c0 + 1]) * rsqrtf(rv[c0 + 1] + 1e-5f) * g[c0 + 1] + be[c0 + 1];
      o1 = o1 > 0.f ? o1 : expm1f(o1);
    }
    float2 o = make_float2(o0, o1);
    *reinterpret_cast<float2*>(&out[(size_t)n * NOUT + c0]) = o;
  } else {
    out[(size_t)n * NOUT + c0] = o0;
  }
}

extern "C" void kernel_launch(void* const* d_in, const int* in_sizes, int n_in,
                              void* d_out, int out_size, void* d_ws, size_t ws_size,
                              hipStream_t stream) {
  const float* x   = (const float*)d_in[0];
  const int*   ei  = (const int*)d_in[1];
  const float* W1  = (const float*)d_in[2];
  const float* as1 = (const float*)d_in[3];
  const float* ad1 = (const float*)d_in[4];
  const float* b1  = (const float*)d_in[5];
  const float* g1  = (const float*)d_in[6];
  const float* be1 = (const float*)d_in[7];
  const float* rm1 = (const float*)d_in[8];
  const float* rv1 = (const float*)d_in[9];
  const float* W2  = (const float*)d_in[10];
  const float* as2 = (const float*)d_in[11];
  const float* ad2 = (const float*)d_in[12];
  const float* b2  = (const float*)d_in[13];
  const float* g2  = (const float*)d_in[14];
  const float* be2 = (const float*)d_in[15];
  const float* rm2 = (const float*)d_in[16];
  const float* rv2 = (const float*)d_in[17];
  const float* W3  = (const float*)d_in[18];
  const float* as3 = (const float*)d_in[19];
  const float* ad3 = (const float*)d_in[20];
  const float* b3  = (const float*)d_in[21];

  const int N = in_sizes[0] / 128;
  const int E = in_sizes[1] / 2;
  float* out = (float*)d_out;

  // workspace layout
  float* A    = (float*)d_ws;                    // N*128
  float* B    = A + (size_t)N * 128;             // N*128
  float* ssrc = B + (size_t)N * 128;             // N*4
  float* sdst = ssrc + (size_t)N * 4;            // N*4
  int* deg    = (int*)(sdst + (size_t)N * 4);    // N
  int* rowptr = deg + N;                         // N+1
  int* cursor = rowptr + (N + 1);                // N
  int* col    = cursor + N;                      // E

  const int GB = 2048;
  const int aggrB = CDIV(N, 4);                  // one wave per node, 4 waves/block

  // ---------------- CSR build (by dst), reused by all 3 layers ----------------
  hipMemsetAsync(deg, 0, (size_t)N * sizeof(int), stream);
  hist_kernel<<<CDIV(E, 256), 256, 0, stream>>>(ei, E, deg);
  scan_kernel<<<1, 1024, 0, stream>>>(deg, rowptr, cursor, N);
  scatter_kernel<<<CDIV(E, 256), 256, 0, stream>>>(ei, E, cursor, col);

  // ---------------- layer 1: GAT(128 -> 4x32) + BN + ELU ----------------
  gemm_k128<128><<<GB, 256, 0, stream>>>(x, W1, A, N);
  scores_kernel<4, 32><<<CDIV(N * 4, 256), 256, 0, stream>>>(A, as1, ad1, ssrc, sdst, N);
  gat_aggr_csr<4, 32, 2, true><<<aggrB, 256, 0, stream>>>(rowptr, col, A, ssrc, sdst,
                                                          b1, g1, be1, rm1, rv1, B, N);

  // ---------------- layer 2: GAT(128 -> 4x32) + BN + ELU ----------------
  gemm_k128<128><<<GB, 256, 0, stream>>>(B, W2, A, N);
  scores_kernel<4, 32><<<CDIV(N * 4, 256), 256, 0, stream>>>(A, as2, ad2, ssrc, sdst, N);
  gat_aggr_csr<4, 32, 2, true><<<aggrB, 256, 0, stream>>>(rowptr, col, A, ssrc, sdst,
                                                          b2, g2, be2, rm2, rv2, B, N);

  // ---------------- layer 3: GAT(128 -> 64, heads=1, no BN) ----------------
  gemm_k128<64><<<GB, 256, 0, stream>>>(B, W3, A, N);
  scores_kernel<1, 64><<<CDIV(N, 256), 256, 0, stream>>>(A, as3, ad3, ssrc, sdst, N);
  gat_aggr_csr<1, 64, 1, false><<<aggrB, 256, 0, stream>>>(rowptr, col, A, ssrc, sdst,
                                                           b3, b3, b3, b3, b3, out, N);
}

// Round 3
// 1060.019 us; speedup vs baseline: 4.6026x; 1.2033x over previous
//
#include <hip/hip_runtime.h>

#define CDIV(a,b) (((a)+(b)-1)/(b))

// ---------------- GEMM: Y[n, NOUT] = X[n,128] @ W[128, NOUT] ----------------
template<int NOUT>
__global__ __launch_bounds__(256) void gemm_k128(const float* __restrict__ X,
                                                 const float* __restrict__ W,
                                                 float* __restrict__ Y, int nrows) {
  constexpr int K = 128;
  constexpr int TPR = NOUT / 4;      // threads per row (32 for 128, 16 for 64)
  constexpr int RPB = 256 / TPR;     // rows per block-iter (8 or 16)
  __shared__ float Ws[K * NOUT];
  __shared__ float Xs[RPB][K];
  for (int i = threadIdx.x; i < K * NOUT; i += 256) Ws[i] = W[i];
  const int rg = threadIdx.x / TPR;
  const int cg = threadIdx.x % TPR;
  const int c0 = cg * 4;
  for (int base = blockIdx.x * RPB; base < nrows; base += gridDim.x * RPB) {
    __syncthreads();   // first iter: covers Ws staging; later: protects Xs reuse
    for (int i = threadIdx.x; i < RPB * K; i += 256) {
      int r = i >> 7, k = i & 127;
      int row = base + r;
      Xs[r][k] = (row < nrows) ? X[(size_t)row * K + k] : 0.f;
    }
    __syncthreads();
    int row = base + rg;
    if (row < nrows) {
      float a0 = 0.f, a1 = 0.f, a2 = 0.f, a3 = 0.f;
      #pragma unroll 4
      for (int k = 0; k < K; ++k) {
        float xv = Xs[rg][k];
        float4 w = *reinterpret_cast<const float4*>(&Ws[k * NOUT + c0]);
        a0 += xv * w.x; a1 += xv * w.y; a2 += xv * w.z; a3 += xv * w.w;
      }
      float4 o = make_float4(a0, a1, a2, a3);
      *reinterpret_cast<float4*>(&Y[(size_t)row * NOUT + c0]) = o;
    }
  }
}

// --------- per-node attention scores: s_src/s_dst[n,h] = <h[n,h,:], a_{s,d}[h,:]> ---------
template<int HEADS, int CH>
__global__ __launch_bounds__(256) void scores_kernel(const float* __restrict__ Hf,
                                                     const float* __restrict__ as_,
                                                     const float* __restrict__ ad_,
                                                     float* __restrict__ ssrc,
                                                     float* __restrict__ sdst, int n) {
  int t = blockIdx.x * blockDim.x + threadIdx.x;
  if (t >= n * HEADS) return;
  int hd = t % HEADS;
  const float* hp = Hf + (size_t)t * CH;   // t == node*HEADS + hd, rows contiguous
  float a = 0.f, b = 0.f;
  #pragma unroll
  for (int c = 0; c < CH; ++c) {
    float v = hp[c];
    a += v * as_[hd * CH + c];
    b += v * ad_[hd * CH + c];
  }
  ssrc[t] = a; sdst[t] = b;
}

// ---------------- CSR build: histogram of dst ----------------
__global__ __launch_bounds__(256) void hist_kernel(const int* __restrict__ ei, int E,
                                                   int* __restrict__ deg) {
  int e = blockIdx.x * blockDim.x + threadIdx.x;
  if (e >= E) return;
  atomicAdd(&deg[ei[E + e]], 1);
}

// ---------------- parallel scan, step 1: per-block (1024-chunk) sums ----------------
__global__ __launch_bounds__(256) void scan_blocksums(const int* __restrict__ deg,
                                                      int* __restrict__ bsum, int N) {
  __shared__ int red[256];
  int base = blockIdx.x * 1024 + threadIdx.x * 4;
  int s = 0;
  #pragma unroll
  for (int i = 0; i < 4; ++i) { int idx = base + i; if (idx < N) s += deg[idx]; }
  red[threadIdx.x] = s;
  __syncthreads();
  for (int off = 128; off > 0; off >>= 1) {
    if (threadIdx.x < off) red[threadIdx.x] += red[threadIdx.x + off];
    __syncthreads();
  }
  if (threadIdx.x == 0) bsum[blockIdx.x] = red[0];
}

// ---------------- parallel scan, step 2: exclusive scan of block sums (nb <= 1024) ----------------
__global__ __launch_bounds__(1024) void scan_bsum(int* __restrict__ bsum, int nb) {
  __shared__ int sh[1024];
  int t = threadIdx.x;
  int v = (t < nb) ? bsum[t] : 0;
  sh[t] = v;
  __syncthreads();
  for (int off = 1; off < 1024; off <<= 1) {
    int tmp = (t >= off) ? sh[t - off] : 0;
    __syncthreads();
    sh[t] += tmp;
    __syncthreads();
  }
  if (t < nb) bsum[t] = sh[t] - v;   // exclusive
}

// ---------------- parallel scan, step 3: per-block rescan + offset, emit rowptr/cursor ----------------
__global__ __launch_bounds__(256) void scan_final(const int* __restrict__ deg,
                                                  const int* __restrict__ bsum,
                                                  int* __restrict__ rowptr,
                                                  int* __restrict__ cursor, int N) {
  __shared__ int sh[256];
  const int t = threadIdx.x;
  const int base = blockIdx.x * 1024 + t * 4;
  int d[4] = {0, 0, 0, 0};
  #pragma unroll
  for (int i = 0; i < 4; ++i) if (base + i < N) d[i] = deg[base + i];
  int s = d[0] + d[1] + d[2] + d[3];
  sh[t] = s;
  __syncthreads();
  for (int off = 1; off < 256; off <<= 1) {
    int tmp = (t >= off) ? sh[t - off] : 0;
    __syncthreads();
    sh[t] += tmp;
    __syncthreads();
  }
  int run = bsum[blockIdx.x] + sh[t] - s;   // exclusive prefix for this thread
  #pragma unroll
  for (int i = 0; i < 4; ++i) {
    if (base + i < N) { rowptr[base + i] = run; cursor[base + i] = run; run += d[i]; }
  }
  if (blockIdx.x == gridDim.x - 1 && t == 255) rowptr[N] = run;   // total (= E)
}

// ---------------- CSR build: scatter src ids into per-dst buckets ----------------
__global__ __launch_bounds__(256) void scatter_kernel(const int* __restrict__ ei, int E,
                                                      int* __restrict__ cursor,
                                                      int* __restrict__ col) {
  int e = blockIdx.x * blockDim.x + threadIdx.x;
  if (e >= E) return;
  int d = ei[E + e];
  int pos = atomicAdd(&cursor[d], 1);
  col[pos] = ei[e];
}

// --------- fused GAT aggregation: one wave per node, online softmax over CSR ---------
template<int HEADS, int CH, int VEC, bool BN>   // NOUT = HEADS*CH; VEC = NOUT/64
__global__ __launch_bounds__(256) void gat_aggr_csr(
    const int* __restrict__ rowptr, const int* __restrict__ col,
    const float* __restrict__ Hf,
    const float* __restrict__ ssrc, const float* __restrict__ sdst,
    const float* __restrict__ bias, const float* __restrict__ g,
    const float* __restrict__ be, const float* __restrict__ rm,
    const float* __restrict__ rv,
    float* __restrict__ out, int N) {
  constexpr int NOUT = HEADS * CH;
  const int wid = blockIdx.x * 4 + (threadIdx.x >> 6);
  const int lane = threadIdx.x & 63;
  if (wid >= N) return;
  const int n = wid;
  const int c0 = lane * VEC;
  const int head = c0 / CH;
  const float sd = sdst[n * HEADS + head];

  // self loop first (guarantees denominator > 0)
  float l = ssrc[n * HEADS + head] + sd;
  l = l > 0.f ? l : 0.2f * l;
  float m = l, s = 1.f;
  float a0 = Hf[(size_t)n * NOUT + c0];
  float a1 = (VEC == 2) ? Hf[(size_t)n * NOUT + c0 + 1] : 0.f;

  const int beg = rowptr[n], end = rowptr[n + 1];
  for (int e = beg; e < end; ++e) {
    int src = col[e];
    float lg = ssrc[src * HEADS + head] + sd;
    lg = lg > 0.f ? lg : 0.2f * lg;
    float nm = fmaxf(m, lg);
    float r = __expf(m - nm);
    float p = __expf(lg - nm);
    float h0 = Hf[(size_t)src * NOUT + c0];
    float h1 = (VEC == 2) ? Hf[(size_t)src * NOUT + c0 + 1] : 0.f;
    a0 = a0 * r + p * h0;
    a1 = a1 * r + p * h1;
    s = s * r + p;
    m = nm;
  }
  const float inv = 1.f / s;

  float o0 = a0 * inv + bias[c0];
  if (BN) {
    o0 = (o0 - rm[c0]) * rsqrtf(rv[c0] + 1e-5f) * g[c0] + be[c0];
    o0 = o0 > 0.f ? o0 : expm1f(o0);
  }
  if (VEC == 2) {
    float o1 = a1 * inv + bias[c0 + 1];
    if (BN) {
      o1 = (o1 - rm[c0 + 1]) * rsqrtf(rv[c0 + 1] + 1e-5f) * g[c0 + 1] + be[c0 + 1];
      o1 = o1 > 0.f ? o1 : expm1f(o1);
    }
    float2 o = make_float2(o0, o1);
    *reinterpret_cast<float2*>(&out[(size_t)n * NOUT + c0]) = o;
  } else {
    out[(size_t)n * NOUT + c0] = o0;
  }
}

extern "C" void kernel_launch(void* const* d_in, const int* in_sizes, int n_in,
                              void* d_out, int out_size, void* d_ws, size_t ws_size,
                              hipStream_t stream) {
  const float* x   = (const float*)d_in[0];
  const int*   ei  = (const int*)d_in[1];
  const float* W1  = (const float*)d_in[2];
  const float* as1 = (const float*)d_in[3];
  const float* ad1 = (const float*)d_in[4];
  const float* b1  = (const float*)d_in[5];
  const float* g1  = (const float*)d_in[6];
  const float* be1 = (const float*)d_in[7];
  const float* rm1 = (const float*)d_in[8];
  const float* rv1 = (const float*)d_in[9];
  const float* W2  = (const float*)d_in[10];
  const float* as2 = (const float*)d_in[11];
  const float* ad2 = (const float*)d_in[12];
  const float* b2  = (const float*)d_in[13];
  const float* g2  = (const float*)d_in[14];
  const float* be2 = (const float*)d_in[15];
  const float* rm2 = (const float*)d_in[16];
  const float* rv2 = (const float*)d_in[17];
  const float* W3  = (const float*)d_in[18];
  const float* as3 = (const float*)d_in[19];
  const float* ad3 = (const float*)d_in[20];
  const float* b3  = (const float*)d_in[21];

  const int N = in_sizes[0] / 128;
  const int E = in_sizes[1] / 2;
  float* out = (float*)d_out;

  // workspace layout
  float* A    = (float*)d_ws;                    // N*128
  float* B    = A + (size_t)N * 128;             // N*128
  float* ssrc = B + (size_t)N * 128;             // N*4
  float* sdst = ssrc + (size_t)N * 4;            // N*4
  int* deg    = (int*)(sdst + (size_t)N * 4);    // N
  int* rowptr = deg + N;                         // N+1
  int* cursor = rowptr + (N + 1);                // N
  int* col    = cursor + N;                      // E
  int* bsum   = col + E;                         // <=1024

  const int GB = 2048;
  const int aggrB = CDIV(N, 4);                  // one wave per node, 4 waves/block
  const int nb = CDIV(N, 1024);                  // scan blocks

  // ---------------- CSR build (by dst), reused by all 3 layers ----------------
  hipMemsetAsync(deg, 0, (size_t)N * sizeof(int), stream);
  hist_kernel<<<CDIV(E, 256), 256, 0, stream>>>(ei, E, deg);
  scan_blocksums<<<nb, 256, 0, stream>>>(deg, bsum, N);
  scan_bsum<<<1, 1024, 0, stream>>>(bsum, nb);
  scan_final<<<nb, 256, 0, stream>>>(deg, bsum, rowptr, cursor, N);
  scatter_kernel<<<CDIV(E, 256), 256, 0, stream>>>(ei, E, cursor, col);

  // ---------------- layer 1: GAT(128 -> 4x32) + BN + ELU ----------------
  gemm_k128<128><<<GB, 256, 0, stream>>>(x, W1, A, N);
  scores_kernel<4, 32><<<CDIV(N * 4, 256), 256, 0, stream>>>(A, as1, ad1, ssrc, sdst, N);
  gat_aggr_csr<4, 32, 2, true><<<aggrB, 256, 0, stream>>>(rowptr, col, A, ssrc, sdst,
                                                          b1, g1, be1, rm1, rv1, B, N);

  // ---------------- layer 2: GAT(128 -> 4x32) + BN + ELU ----------------
  gemm_k128<128><<<GB, 256, 0, stream>>>(B, W2, A, N);
  scores_kernel<4, 32><<<CDIV(N * 4, 256), 256, 0, stream>>>(A, as2, ad2, ssrc, sdst, N);
  gat_aggr_csr<4, 32, 2, true><<<aggrB, 256, 0, stream>>>(rowptr, col, A, ssrc, sdst,
                                                          b2, g2, be2, rm2, rv2, B, N);

  // ---------------- layer 3: GAT(128 -> 64, heads=1, no BN) ----------------
  gemm_k128<64><<<GB, 256, 0, stream>>>(B, W3, A, N);
  scores_kernel<1, 64><<<CDIV(N, 256), 256, 0, stream>>>(A, as3, ad3, ssrc, sdst, N);
  gat_aggr_csr<1, 64, 1, false><<<aggrB, 256, 0, stream>>>(rowptr, col, A, ssrc, sdst,
                                                           b3, b3, b3, b3, b3, out, N);
}

// Round 4
// 1028.970 us; speedup vs baseline: 4.7415x; 1.0302x over previous
//
#include <hip/hip_runtime.h>
#include <hip/hip_fp16.h>

#define CDIV(a,b) (((a)+(b)-1)/(b))

// ---------------- GEMM: Y[n, NOUT] = X[n,128] @ W[128, NOUT], fp32 in, fp16 out ----------------
template<int NOUT>
__global__ __launch_bounds__(256) void gemm_k128(const float* __restrict__ X,
                                                 const float* __restrict__ W,
                                                 __half* __restrict__ Y, int nrows) {
  constexpr int K = 128;
  constexpr int TPR = NOUT / 4;      // threads per row (32 for 128, 16 for 64)
  constexpr int RPB = 256 / TPR;     // rows per block-iter (8 or 16)
  __shared__ float Ws[K * NOUT];
  __shared__ float Xs[RPB][K];
  for (int i = threadIdx.x; i < K * NOUT; i += 256) Ws[i] = W[i];
  const int rg = threadIdx.x / TPR;
  const int cg = threadIdx.x % TPR;
  const int c0 = cg * 4;
  for (int base = blockIdx.x * RPB; base < nrows; base += gridDim.x * RPB) {
    __syncthreads();   // first iter: covers Ws staging; later: protects Xs reuse
    for (int i = threadIdx.x; i < RPB * K; i += 256) {
      int r = i >> 7, k = i & 127;
      int row = base + r;
      Xs[r][k] = (row < nrows) ? X[(size_t)row * K + k] : 0.f;
    }
    __syncthreads();
    int row = base + rg;
    if (row < nrows) {
      float a0 = 0.f, a1 = 0.f, a2 = 0.f, a3 = 0.f;
      #pragma unroll 4
      for (int k = 0; k < K; ++k) {
        float xv = Xs[rg][k];
        float4 w = *reinterpret_cast<const float4*>(&Ws[k * NOUT + c0]);
        a0 += xv * w.x; a1 += xv * w.y; a2 += xv * w.z; a3 += xv * w.w;
      }
      ushort4 o;
      o.x = __half_as_ushort(__float2half_rn(a0));
      o.y = __half_as_ushort(__float2half_rn(a1));
      o.z = __half_as_ushort(__float2half_rn(a2));
      o.w = __half_as_ushort(__float2half_rn(a3));
      *reinterpret_cast<ushort4*>(&Y[(size_t)row * NOUT + c0]) = o;
    }
  }
}

// --------- per-node attention scores: s_src/s_dst[n,h] = <h[n,h,:], a_{s,d}[h,:]> ---------
template<int HEADS, int CH>
__global__ __launch_bounds__(256) void scores_kernel(const __half* __restrict__ Hf,
                                                     const float* __restrict__ as_,
                                                     const float* __restrict__ ad_,
                                                     float* __restrict__ ssrc,
                                                     float* __restrict__ sdst, int n) {
  int t = blockIdx.x * blockDim.x + threadIdx.x;
  if (t >= n * HEADS) return;
  int hd = t % HEADS;
  const __half2* hp2 = reinterpret_cast<const __half2*>(Hf + (size_t)t * CH);
  float a = 0.f, b = 0.f;
  #pragma unroll
  for (int c2 = 0; c2 < CH / 2; ++c2) {
    float2 v = __half22float2(hp2[c2]);
    a += v.x * as_[hd * CH + 2 * c2] + v.y * as_[hd * CH + 2 * c2 + 1];
    b += v.x * ad_[hd * CH + 2 * c2] + v.y * ad_[hd * CH + 2 * c2 + 1];
  }
  ssrc[t] = a; sdst[t] = b;
}

// ---------------- CSR build: histogram of dst ----------------
__global__ __launch_bounds__(256) void hist_kernel(const int* __restrict__ ei, int E,
                                                   int* __restrict__ deg) {
  int e = blockIdx.x * blockDim.x + threadIdx.x;
  if (e >= E) return;
  atomicAdd(&deg[ei[E + e]], 1);
}

// ---------------- parallel scan, step 1: per-block (1024-chunk) sums ----------------
__global__ __launch_bounds__(256) void scan_blocksums(const int* __restrict__ deg,
                                                      int* __restrict__ bsum, int N) {
  __shared__ int red[256];
  int base = blockIdx.x * 1024 + threadIdx.x * 4;
  int s = 0;
  #pragma unroll
  for (int i = 0; i < 4; ++i) { int idx = base + i; if (idx < N) s += deg[idx]; }
  red[threadIdx.x] = s;
  __syncthreads();
  for (int off = 128; off > 0; off >>= 1) {
    if (threadIdx.x < off) red[threadIdx.x] += red[threadIdx.x + off];
    __syncthreads();
  }
  if (threadIdx.x == 0) bsum[blockIdx.x] = red[0];
}

// ---------------- parallel scan, step 2: exclusive scan of block sums (nb <= 1024) ----------------
__global__ __launch_bounds__(1024) void scan_bsum(int* __restrict__ bsum, int nb) {
  __shared__ int sh[1024];
  int t = threadIdx.x;
  int v = (t < nb) ? bsum[t] : 0;
  sh[t] = v;
  __syncthreads();
  for (int off = 1; off < 1024; off <<= 1) {
    int tmp = (t >= off) ? sh[t - off] : 0;
    __syncthreads();
    sh[t] += tmp;
    __syncthreads();
  }
  if (t < nb) bsum[t] = sh[t] - v;   // exclusive
}

// ---------------- parallel scan, step 3: per-block rescan + offset, emit rowptr/cursor ----------------
__global__ __launch_bounds__(256) void scan_final(const int* __restrict__ deg,
                                                  const int* __restrict__ bsum,
                                                  int* __restrict__ rowptr,
                                                  int* __restrict__ cursor, int N) {
  __shared__ int sh[256];
  const int t = threadIdx.x;
  const int base = blockIdx.x * 1024 + t * 4;
  int d[4] = {0, 0, 0, 0};
  #pragma unroll
  for (int i = 0; i < 4; ++i) if (base + i < N) d[i] = deg[base + i];
  int s = d[0] + d[1] + d[2] + d[3];
  sh[t] = s;
  __syncthreads();
  for (int off = 1; off < 256; off <<= 1) {
    int tmp = (t >= off) ? sh[t - off] : 0;
    __syncthreads();
    sh[t] += tmp;
    __syncthreads();
  }
  int run = bsum[blockIdx.x] + sh[t] - s;   // exclusive prefix for this thread
  #pragma unroll
  for (int i = 0; i < 4; ++i) {
    if (base + i < N) { rowptr[base + i] = run; cursor[base + i] = run; run += d[i]; }
  }
  if (blockIdx.x == gridDim.x - 1 && t == 255) rowptr[N] = run;   // total (= E)
}

// ---------------- CSR build: scatter src ids into per-dst buckets ----------------
__global__ __launch_bounds__(256) void scatter_kernel(const int* __restrict__ ei, int E,
                                                      int* __restrict__ cursor,
                                                      int* __restrict__ col) {
  int e = blockIdx.x * blockDim.x + threadIdx.x;
  if (e >= E) return;
  int d = ei[E + e];
  int pos = atomicAdd(&cursor[d], 1);
  col[pos] = ei[e];
}

// --------- fused GAT aggregation: one wave per node, online softmax over CSR ---------
template<int HEADS, int CH, int VEC, bool BN>   // NOUT = HEADS*CH; VEC = NOUT/64
__global__ __launch_bounds__(256) void gat_aggr_csr(
    const int* __restrict__ rowptr, const int* __restrict__ col,
    const __half* __restrict__ Hf,
    const float* __restrict__ ssrc, const float* __restrict__ sdst,
    const float* __restrict__ bias, const float* __restrict__ g,
    const float* __restrict__ be, const float* __restrict__ rm,
    const float* __restrict__ rv,
    float* __restrict__ out, int N) {
  constexpr int NOUT = HEADS * CH;
  const int wid = blockIdx.x * 4 + (threadIdx.x >> 6);
  const int lane = threadIdx.x & 63;
  if (wid >= N) return;
  const int n = wid;
  const int c0 = lane * VEC;
  const int head = c0 / CH;
  const float sd = sdst[n * HEADS + head];

  // self loop first (guarantees denominator > 0)
  float l = ssrc[n * HEADS + head] + sd;
  l = l > 0.f ? l : 0.2f * l;
  float m = l, s = 1.f;
  float a0, a1 = 0.f;
  if (VEC == 2) {
    float2 hf = __half22float2(*reinterpret_cast<const __half2*>(&Hf[(size_t)n * NOUT + c0]));
    a0 = hf.x; a1 = hf.y;
  } else {
    a0 = __half2float(Hf[(size_t)n * NOUT + c0]);
  }

  const int beg = rowptr[n], end = rowptr[n + 1];
  for (int e = beg; e < end; ++e) {
    int src = col[e];
    float lg = ssrc[src * HEADS + head] + sd;
    lg = lg > 0.f ? lg : 0.2f * lg;
    float nm = fmaxf(m, lg);
    float r = __expf(m - nm);
    float p = __expf(lg - nm);
    float h0, h1 = 0.f;
    if (VEC == 2) {
      float2 hf = __half22float2(*reinterpret_cast<const __half2*>(&Hf[(size_t)src * NOUT + c0]));
      h0 = hf.x; h1 = hf.y;
    } else {
      h0 = __half2float(Hf[(size_t)src * NOUT + c0]);
    }
    a0 = a0 * r + p * h0;
    a1 = a1 * r + p * h1;
    s = s * r + p;
    m = nm;
  }
  const float inv = 1.f / s;

  float o0 = a0 * inv + bias[c0];
  if (BN) {
    o0 = (o0 - rm[c0]) * rsqrtf(rv[c0] + 1e-5f) * g[c0] + be[c0];
    o0 = o0 > 0.f ? o0 : expm1f(o0);
  }
  if (VEC == 2) {
    float o1 = a1 * inv + bias[c0 + 1];
    if (BN) {
      o1 = (o1 - rm[c0 + 1]) * rsqrtf(rv[c0 + 1] + 1e-5f) * g[c0 + 1] + be[c0 + 1];
      o1 = o1 > 0.f ? o1 : expm1f(o1);
    }
    float2 o = make_float2(o0, o1);
    *reinterpret_cast<float2*>(&out[(size_t)n * NOUT + c0]) = o;
  } else {
    out[(size_t)n * NOUT + c0] = o0;
  }
}

extern "C" void kernel_launch(void* const* d_in, const int* in_sizes, int n_in,
                              void* d_out, int out_size, void* d_ws, size_t ws_size,
                              hipStream_t stream) {
  const float* x   = (const float*)d_in[0];
  const int*   ei  = (const int*)d_in[1];
  const float* W1  = (const float*)d_in[2];
  const float* as1 = (const float*)d_in[3];
  const float* ad1 = (const float*)d_in[4];
  const float* b1  = (const float*)d_in[5];
  const float* g1  = (const float*)d_in[6];
  const float* be1 = (const float*)d_in[7];
  const float* rm1 = (const float*)d_in[8];
  const float* rv1 = (const float*)d_in[9];
  const float* W2  = (const float*)d_in[10];
  const float* as2 = (const float*)d_in[11];
  const float* ad2 = (const float*)d_in[12];
  const float* b2  = (const float*)d_in[13];
  const float* g2  = (const float*)d_in[14];
  const float* be2 = (const float*)d_in[15];
  const float* rm2 = (const float*)d_in[16];
  const float* rv2 = (const float*)d_in[17];
  const float* W3  = (const float*)d_in[18];
  const float* as3 = (const float*)d_in[19];
  const float* ad3 = (const float*)d_in[20];
  const float* b3  = (const float*)d_in[21];

  const int N = in_sizes[0] / 128;
  const int E = in_sizes[1] / 2;
  float* out = (float*)d_out;

  // workspace layout
  __half* A   = (__half*)d_ws;                   // N*128 fp16 (h buffer)
  float* B    = (float*)(A + (size_t)N * 128);   // N*128 fp32 (layer output)
  float* ssrc = B + (size_t)N * 128;             // N*4
  float* sdst = ssrc + (size_t)N * 4;            // N*4
  int* deg    = (int*)(sdst + (size_t)N * 4);    // N
  int* rowptr = deg + N;                         // N+1
  int* cursor = rowptr + (N + 1);                // N
  int* col    = cursor + N;                      // E
  int* bsum   = col + E;                         // <=1024

  const int GB = 2048;
  const int aggrB = CDIV(N, 4);                  // one wave per node, 4 waves/block
  const int nb = CDIV(N, 1024);                  // scan blocks

  // ---------------- CSR build (by dst), reused by all 3 layers ----------------
  hipMemsetAsync(deg, 0, (size_t)N * sizeof(int), stream);
  hist_kernel<<<CDIV(E, 256), 256, 0, stream>>>(ei, E, deg);
  scan_blocksums<<<nb, 256, 0, stream>>>(deg, bsum, N);
  scan_bsum<<<1, 1024, 0, stream>>>(bsum, nb);
  scan_final<<<nb, 256, 0, stream>>>(deg, bsum, rowptr, cursor, N);
  scatter_kernel<<<CDIV(E, 256), 256, 0, stream>>>(ei, E, cursor, col);

  // ---------------- layer 1: GAT(128 -> 4x32) + BN + ELU ----------------
  gemm_k128<128><<<GB, 256, 0, stream>>>(x, W1, A, N);
  scores_kernel<4, 32><<<CDIV(N * 4, 256), 256, 0, stream>>>(A, as1, ad1, ssrc, sdst, N);
  gat_aggr_csr<4, 32, 2, true><<<aggrB, 256, 0, stream>>>(rowptr, col, A, ssrc, sdst,
                                                          b1, g1, be1, rm1, rv1, B, N);

  // ---------------- layer 2: GAT(128 -> 4x32) + BN + ELU ----------------
  gemm_k128<128><<<GB, 256, 0, stream>>>(B, W2, A, N);
  scores_kernel<4, 32><<<CDIV(N * 4, 256), 256, 0, stream>>>(A, as2, ad2, ssrc, sdst, N);
  gat_aggr_csr<4, 32, 2, true><<<aggrB, 256, 0, stream>>>(rowptr, col, A, ssrc, sdst,
                                                          b2, g2, be2, rm2, rv2, B, N);

  // ---------------- layer 3: GAT(128 -> 64, heads=1, no BN) ----------------
  gemm_k128<64><<<GB, 256, 0, stream>>>(B, W3, A, N);
  scores_kernel<1, 64><<<CDIV(N, 256), 256, 0, stream>>>(A, as3, ad3, ssrc, sdst, N);
  gat_aggr_csr<1, 64, 1, false><<<aggrB, 256, 0, stream>>>(rowptr, col, A, ssrc, sdst,
                                                           b3, b3, b3, b3, b3, out, N);
}

// Round 5
// 840.123 us; speedup vs baseline: 5.8073x; 1.2248x over previous
//
#include <hip/hip_runtime.h>
#include <hip/hip_fp16.h>

#define CDIV(a,b) (((a)+(b)-1)/(b))

// ---------------- GEMM: Y[n, NOUT] = X[n,128] @ W[128, NOUT], fp32 in, fp16 out ----------------
template<int NOUT>
__global__ __launch_bounds__(256) void gemm_k128(const float* __restrict__ X,
                                                 const float* __restrict__ W,
                                                 __half* __restrict__ Y, int nrows) {
  constexpr int K = 128;
  constexpr int TPR = NOUT / 4;      // threads per row (32 for 128, 16 for 64)
  constexpr int RPB = 256 / TPR;     // rows per block-iter (8 or 16)
  __shared__ float Ws[K * NOUT];
  __shared__ float Xs[RPB][K];
  for (int i = threadIdx.x; i < K * NOUT; i += 256) Ws[i] = W[i];
  const int rg = threadIdx.x / TPR;
  const int cg = threadIdx.x % TPR;
  const int c0 = cg * 4;
  for (int base = blockIdx.x * RPB; base < nrows; base += gridDim.x * RPB) {
    __syncthreads();   // first iter: covers Ws staging; later: protects Xs reuse
    for (int i = threadIdx.x; i < RPB * K; i += 256) {
      int r = i >> 7, k = i & 127;
      int row = base + r;
      Xs[r][k] = (row < nrows) ? X[(size_t)row * K + k] : 0.f;
    }
    __syncthreads();
    int row = base + rg;
    if (row < nrows) {
      float a0 = 0.f, a1 = 0.f, a2 = 0.f, a3 = 0.f;
      #pragma unroll 4
      for (int k = 0; k < K; ++k) {
        float xv = Xs[rg][k];
        float4 w = *reinterpret_cast<const float4*>(&Ws[k * NOUT + c0]);
        a0 += xv * w.x; a1 += xv * w.y; a2 += xv * w.z; a3 += xv * w.w;
      }
      ushort4 o;
      o.x = __half_as_ushort(__float2half_rn(a0));
      o.y = __half_as_ushort(__float2half_rn(a1));
      o.z = __half_as_ushort(__float2half_rn(a2));
      o.w = __half_as_ushort(__float2half_rn(a3));
      *reinterpret_cast<ushort4*>(&Y[(size_t)row * NOUT + c0]) = o;
    }
  }
}

// --------- per-node attention scores: s_src/s_dst[n,h] = <h[n,h,:], a_{s,d}[h,:]> ---------
template<int HEADS, int CH>
__global__ __launch_bounds__(256) void scores_kernel(const __half* __restrict__ Hf,
                                                     const float* __restrict__ as_,
                                                     const float* __restrict__ ad_,
                                                     float* __restrict__ ssrc,
                                                     float* __restrict__ sdst, int n) {
  int t = blockIdx.x * blockDim.x + threadIdx.x;
  if (t >= n * HEADS) return;
  int hd = t % HEADS;
  const __half2* hp2 = reinterpret_cast<const __half2*>(Hf + (size_t)t * CH);
  float a = 0.f, b = 0.f;
  #pragma unroll
  for (int c2 = 0; c2 < CH / 2; ++c2) {
    float2 v = __half22float2(hp2[c2]);
    a += v.x * as_[hd * CH + 2 * c2] + v.y * as_[hd * CH + 2 * c2 + 1];
    b += v.x * ad_[hd * CH + 2 * c2] + v.y * ad_[hd * CH + 2 * c2 + 1];
  }
  ssrc[t] = a; sdst[t] = b;
}

// ---------------- CSR build: histogram of dst ----------------
__global__ __launch_bounds__(256) void hist_kernel(const int* __restrict__ ei, int E,
                                                   int* __restrict__ deg) {
  int e = blockIdx.x * blockDim.x + threadIdx.x;
  if (e >= E) return;
  atomicAdd(&deg[ei[E + e]], 1);
}

// ---------------- parallel scan, step 1: per-block (1024-chunk) sums ----------------
__global__ __launch_bounds__(256) void scan_blocksums(const int* __restrict__ deg,
                                                      int* __restrict__ bsum, int N) {
  __shared__ int red[256];
  int base = blockIdx.x * 1024 + threadIdx.x * 4;
  int s = 0;
  #pragma unroll
  for (int i = 0; i < 4; ++i) { int idx = base + i; if (idx < N) s += deg[idx]; }
  red[threadIdx.x] = s;
  __syncthreads();
  for (int off = 128; off > 0; off >>= 1) {
    if (threadIdx.x < off) red[threadIdx.x] += red[threadIdx.x + off];
    __syncthreads();
  }
  if (threadIdx.x == 0) bsum[blockIdx.x] = red[0];
}

// ---------------- parallel scan, step 2: exclusive scan of block sums (nb <= 1024) ----------------
__global__ __launch_bounds__(1024) void scan_bsum(int* __restrict__ bsum, int nb) {
  __shared__ int sh[1024];
  int t = threadIdx.x;
  int v = (t < nb) ? bsum[t] : 0;
  sh[t] = v;
  __syncthreads();
  for (int off = 1; off < 1024; off <<= 1) {
    int tmp = (t >= off) ? sh[t - off] : 0;
    __syncthreads();
    sh[t] += tmp;
    __syncthreads();
  }
  if (t < nb) bsum[t] = sh[t] - v;   // exclusive
}

// ---------------- parallel scan, step 3: per-block rescan + offset, emit rowptr/cursor ----------------
__global__ __launch_bounds__(256) void scan_final(const int* __restrict__ deg,
                                                  const int* __restrict__ bsum,
                                                  int* __restrict__ rowptr,
                                                  int* __restrict__ cursor, int N) {
  __shared__ int sh[256];
  const int t = threadIdx.x;
  const int base = blockIdx.x * 1024 + t * 4;
  int d[4] = {0, 0, 0, 0};
  #pragma unroll
  for (int i = 0; i < 4; ++i) if (base + i < N) d[i] = deg[base + i];
  int s = d[0] + d[1] + d[2] + d[3];
  sh[t] = s;
  __syncthreads();
  for (int off = 1; off < 256; off <<= 1) {
    int tmp = (t >= off) ? sh[t - off] : 0;
    __syncthreads();
    sh[t] += tmp;
    __syncthreads();
  }
  int run = bsum[blockIdx.x] + sh[t] - s;   // exclusive prefix for this thread
  #pragma unroll
  for (int i = 0; i < 4; ++i) {
    if (base + i < N) { rowptr[base + i] = run; cursor[base + i] = run; run += d[i]; }
  }
  if (blockIdx.x == gridDim.x - 1 && t == 255) rowptr[N] = run;   // total (= E)
}

// ---------------- CSR build: scatter src ids into per-dst buckets ----------------
__global__ __launch_bounds__(256) void scatter_kernel(const int* __restrict__ ei, int E,
                                                      int* __restrict__ cursor,
                                                      int* __restrict__ col) {
  int e = blockIdx.x * blockDim.x + threadIdx.x;
  if (e >= E) return;
  int d = ei[E + e];
  int pos = atomicAdd(&cursor[d], 1);
  col[pos] = ei[e];
}

// --------- softmax alphas: wave per node, lanes parallel over (edge-slot, head) ---------
// writes UNNORMALIZED p=exp(lg-m) per edge (fp16, p<=1), self-p and 1/S per (node,head)
template<int HEADS>
__global__ __launch_bounds__(256) void alpha_kernel(
    const int* __restrict__ rowptr, const int* __restrict__ col,
    const float* __restrict__ ssrc, const float* __restrict__ sdst,
    __half* __restrict__ alpha, float* __restrict__ aself,
    float* __restrict__ sinv, int N) {
  constexpr int SLOTS = 64 / HEADS;
  const int wid = blockIdx.x * 4 + (threadIdx.x >> 6);
  if (wid >= N) return;
  const int lane = threadIdx.x & 63;
  const int eslot = lane / HEADS;
  const int head = lane & (HEADS - 1);
  const int n = wid;
  const float sd = sdst[n * HEADS + head];
  const int beg = rowptr[n], end = rowptr[n + 1];

  float lgs = ssrc[n * HEADS + head] + sd;           // self-loop logit
  lgs = lgs > 0.f ? lgs : 0.2f * lgs;
  float m = lgs;
  for (int base = beg; base < end; base += SLOTS) {
    int e = base + eslot;
    if (e < end) {
      int src = col[e];
      float lg = ssrc[src * HEADS + head] + sd;
      lg = lg > 0.f ? lg : 0.2f * lg;
      m = fmaxf(m, lg);
    }
  }
  #pragma unroll
  for (int off = HEADS; off < 64; off <<= 1) m = fmaxf(m, __shfl_xor(m, off));

  float s = 0.f;
  for (int base = beg; base < end; base += SLOTS) {
    int e = base + eslot;
    if (e < end) {
      int src = col[e];
      float lg = ssrc[src * HEADS + head] + sd;
      lg = lg > 0.f ? lg : 0.2f * lg;
      float p = __expf(lg - m);
      alpha[(size_t)e * HEADS + head] = __float2half_rn(p);
      s += p;
    }
  }
  #pragma unroll
  for (int off = HEADS; off < 64; off <<= 1) s += __shfl_xor(s, off);
  float ps = __expf(lgs - m);
  s += ps;
  if (eslot == 0) {
    aself[n * HEADS + head] = ps;
    sinv[n * HEADS + head] = 1.f / s;
  }
}

// --------- aggregation: pure gather-FMA, wave per node, deferred normalization ---------
template<int HEADS, int CH, int VEC, bool BN>   // NOUT = HEADS*CH; VEC = NOUT/64
__global__ __launch_bounds__(256) void aggr2_kernel(
    const int* __restrict__ rowptr, const int* __restrict__ col,
    const __half* __restrict__ Hf,
    const __half* __restrict__ alpha, const float* __restrict__ aself,
    const float* __restrict__ sinv,
    const float* __restrict__ bias, const float* __restrict__ g,
    const float* __restrict__ be, const float* __restrict__ rm,
    const float* __restrict__ rv,
    float* __restrict__ out, int N) {
  constexpr int NOUT = HEADS * CH;
  const int wid = blockIdx.x * 4 + (threadIdx.x >> 6);
  const int lane = threadIdx.x & 63;
  if (wid >= N) return;
  const int n = wid;
  const int c0 = lane * VEC;
  const int head = c0 / CH;

  float a0, a1 = 0.f;
  {
    float asf = aself[n * HEADS + head];
    if (VEC == 2) {
      float2 hf = __half22float2(*reinterpret_cast<const __half2*>(&Hf[(size_t)n * NOUT + c0]));
      a0 = asf * hf.x; a1 = asf * hf.y;
    } else {
      a0 = asf * __half2float(Hf[(size_t)n * NOUT + c0]);
    }
  }

  const int beg = rowptr[n], end = rowptr[n + 1];
  #pragma unroll 4
  for (int e = beg; e < end; ++e) {
    int src = col[e];
    float al = __half2float(alpha[(size_t)e * HEADS + head]);
    if (VEC == 2) {
      float2 hf = __half22float2(*reinterpret_cast<const __half2*>(&Hf[(size_t)src * NOUT + c0]));
      a0 += al * hf.x;
      a1 += al * hf.y;
    } else {
      a0 += al * __half2float(Hf[(size_t)src * NOUT + c0]);
    }
  }

  const float inv = sinv[n * HEADS + head];
  float o0 = a0 * inv + bias[c0];
  if (BN) {
    o0 = (o0 - rm[c0]) * rsqrtf(rv[c0] + 1e-5f) * g[c0] + be[c0];
    o0 = o0 > 0.f ? o0 : expm1f(o0);
  }
  if (VEC == 2) {
    float o1 = a1 * inv + bias[c0 + 1];
    if (BN) {
      o1 = (o1 - rm[c0 + 1]) * rsqrtf(rv[c0 + 1] + 1e-5f) * g[c0 + 1] + be[c0 + 1];
      o1 = o1 > 0.f ? o1 : expm1f(o1);
    }
    float2 o = make_float2(o0, o1);
    *reinterpret_cast<float2*>(&out[(size_t)n * NOUT + c0]) = o;
  } else {
    out[(size_t)n * NOUT + c0] = o0;
  }
}

extern "C" void kernel_launch(void* const* d_in, const int* in_sizes, int n_in,
                              void* d_out, int out_size, void* d_ws, size_t ws_size,
                              hipStream_t stream) {
  const float* x   = (const float*)d_in[0];
  const int*   ei  = (const int*)d_in[1];
  const float* W1  = (const float*)d_in[2];
  const float* as1 = (const float*)d_in[3];
  const float* ad1 = (const float*)d_in[4];
  const float* b1  = (const float*)d_in[5];
  const float* g1  = (const float*)d_in[6];
  const float* be1 = (const float*)d_in[7];
  const float* rm1 = (const float*)d_in[8];
  const float* rv1 = (const float*)d_in[9];
  const float* W2  = (const float*)d_in[10];
  const float* as2 = (const float*)d_in[11];
  const float* ad2 = (const float*)d_in[12];
  const float* b2  = (const float*)d_in[13];
  const float* g2  = (const float*)d_in[14];
  const float* be2 = (const float*)d_in[15];
  const float* rm2 = (const float*)d_in[16];
  const float* rv2 = (const float*)d_in[17];
  const float* W3  = (const float*)d_in[18];
  const float* as3 = (const float*)d_in[19];
  const float* ad3 = (const float*)d_in[20];
  const float* b3  = (const float*)d_in[21];

  const int N = in_sizes[0] / 128;
  const int E = in_sizes[1] / 2;
  float* out = (float*)d_out;

  // workspace layout
  __half* A   = (__half*)d_ws;                   // N*128 fp16 (h buffer)
  float* B    = (float*)(A + (size_t)N * 128);   // N*128 fp32 (layer output)
  float* ssrc = B + (size_t)N * 128;             // N*4
  float* sdst = ssrc + (size_t)N * 4;            // N*4
  int* deg    = (int*)(sdst + (size_t)N * 4);    // N
  int* rowptr = deg + N;                         // N+1
  int* cursor = rowptr + (N + 1);                // N
  int* col    = cursor + N;                      // E
  int* bsum   = col + E;                         // <=1024
  __half* alpha = (__half*)(bsum + 1024);        // E*4 fp16
  float* aself  = (float*)(alpha + (size_t)E * 4); // N*4
  float* sinv   = aself + (size_t)N * 4;         // N*4

  const int GB = 2048;
  const int aggrB = CDIV(N, 4);                  // one wave per node, 4 waves/block
  const int nb = CDIV(N, 1024);                  // scan blocks

  // ---------------- CSR build (by dst), reused by all 3 layers ----------------
  hipMemsetAsync(deg, 0, (size_t)N * sizeof(int), stream);
  hist_kernel<<<CDIV(E, 256), 256, 0, stream>>>(ei, E, deg);
  scan_blocksums<<<nb, 256, 0, stream>>>(deg, bsum, N);
  scan_bsum<<<1, 1024, 0, stream>>>(bsum, nb);
  scan_final<<<nb, 256, 0, stream>>>(deg, bsum, rowptr, cursor, N);
  scatter_kernel<<<CDIV(E, 256), 256, 0, stream>>>(ei, E, cursor, col);

  // ---------------- layer 1: GAT(128 -> 4x32) + BN + ELU ----------------
  gemm_k128<128><<<GB, 256, 0, stream>>>(x, W1, A, N);
  scores_kernel<4, 32><<<CDIV(N * 4, 256), 256, 0, stream>>>(A, as1, ad1, ssrc, sdst, N);
  alpha_kernel<4><<<aggrB, 256, 0, stream>>>(rowptr, col, ssrc, sdst, alpha, aself, sinv, N);
  aggr2_kernel<4, 32, 2, true><<<aggrB, 256, 0, stream>>>(rowptr, col, A, alpha, aself, sinv,
                                                          b1, g1, be1, rm1, rv1, B, N);

  // ---------------- layer 2: GAT(128 -> 4x32) + BN + ELU ----------------
  gemm_k128<128><<<GB, 256, 0, stream>>>(B, W2, A, N);
  scores_kernel<4, 32><<<CDIV(N * 4, 256), 256, 0, stream>>>(A, as2, ad2, ssrc, sdst, N);
  alpha_kernel<4><<<aggrB, 256, 0, stream>>>(rowptr, col, ssrc, sdst, alpha, aself, sinv, N);
  aggr2_kernel<4, 32, 2, true><<<aggrB, 256, 0, stream>>>(rowptr, col, A, alpha, aself, sinv,
                                                          b2, g2, be2, rm2, rv2, B, N);

  // ---------------- layer 3: GAT(128 -> 64, heads=1, no BN) ----------------
  gemm_k128<64><<<GB, 256, 0, stream>>>(B, W3, A, N);
  scores_kernel<1, 64><<<CDIV(N, 256), 256, 0, stream>>>(A, as3, ad3, ssrc, sdst, N);
  alpha_kernel<1><<<aggrB, 256, 0, stream>>>(rowptr, col, ssrc, sdst, alpha, aself, sinv, N);
  aggr2_kernel<1, 64, 1, false><<<aggrB, 256, 0, stream>>>(rowptr, col, A, alpha, aself, sinv,
                                                           b3, b3, b3, b3, b3, out, N);
}

// Round 6
// 602.601 us; speedup vs baseline: 8.0963x; 1.3942x over previous
//
#include <hip/hip_runtime.h>
#include <hip/hip_fp16.h>

#define CDIV(a,b) (((a)+(b)-1)/(b))

typedef _Float16 f16x8 __attribute__((ext_vector_type(8)));
typedef float f32x4 __attribute__((ext_vector_type(4)));

// ---------------- fp32 -> fp16 convert (x input, once per launch) ----------------
__global__ __launch_bounds__(256) void conv_kernel(const float* __restrict__ X,
                                                   __half* __restrict__ Y, int total4) {
  int t = blockIdx.x * blockDim.x + threadIdx.x;
  if (t >= total4) return;
  float4 v = reinterpret_cast<const float4*>(X)[t];
  __half2 a = __floats2half2_rn(v.x, v.y);
  __half2 b = __floats2half2_rn(v.z, v.w);
  reinterpret_cast<__half2*>(Y)[t * 2]     = a;
  reinterpret_cast<__half2*>(Y)[t * 2 + 1] = b;
}

// ---------------- MFMA GEMM: Y[n,NOUT](fp16) = X[n,128](fp16) @ W[128,NOUT](fp32) ----------------
// requires nrows % 16 == 0 (N=100000=6250*16). One wave per 16-row tile, 4 waves/block.
// W staged in LDS fragment-major: element (k,c) at [((s*4+g)*NOUT + c)*8 + i], k=s*32+g*8+i
template<int NOUT>
__global__ __launch_bounds__(256) void gemm_mfma(const __half* __restrict__ Xh,
                                                 const float* __restrict__ W,
                                                 __half* __restrict__ Y, int nrows) {
  constexpr int K = 128;
  constexpr int CT = NOUT / 16;      // col tiles
  __shared__ _Float16 Wt[K * NOUT];
  for (int i = threadIdx.x; i < K * NOUT; i += 256) {
    int k = i / NOUT, c = i % NOUT;
    int s = k >> 5, g = (k >> 3) & 3, e = k & 7;
    Wt[(size_t)((s * 4 + g) * NOUT + c) * 8 + e] = (_Float16)W[i];
  }
  __syncthreads();
  const int wave = threadIdx.x >> 6, lane = threadIdx.x & 63;
  const int g = lane >> 4, r16 = lane & 15;
  const int rt = blockIdx.x * 4 + wave;
  if (rt * 16 >= nrows) return;

  // A fragments: row = lane&15, k = s*32 + g*8 + i  (same bijection used for B)
  const _Float16* xrow = reinterpret_cast<const _Float16*>(Xh)
                         + (size_t)(rt * 16 + r16) * K + g * 8;
  f16x8 a[4];
  #pragma unroll
  for (int s = 0; s < 4; ++s) a[s] = *reinterpret_cast<const f16x8*>(xrow + s * 32);

  f32x4 acc[CT];
  #pragma unroll
  for (int ct = 0; ct < CT; ++ct) acc[ct] = (f32x4){0.f, 0.f, 0.f, 0.f};

  #pragma unroll
  for (int ct = 0; ct < CT; ++ct) {
    #pragma unroll
    for (int s = 0; s < 4; ++s) {
      f16x8 b = *reinterpret_cast<const f16x8*>(&Wt[(size_t)((s * 4 + g) * NOUT + ct * 16 + r16) * 8]);
      acc[ct] = __builtin_amdgcn_mfma_f32_16x16x32_f16(a[s], b, acc[ct], 0, 0, 0);
    }
  }
  // C/D: col = lane&15, row = (lane>>4)*4 + reg   [verified layout]
  const int row0 = rt * 16 + g * 4;
  #pragma unroll
  for (int ct = 0; ct < CT; ++ct) {
    #pragma unroll
    for (int r = 0; r < 4; ++r) {
      Y[(size_t)(row0 + r) * NOUT + ct * 16 + r16] = __float2half_rn(acc[ct][r]);
    }
  }
}

// --------- per-node attention scores: s_src/s_dst[n,h] = <h[n,h,:], a_{s,d}[h,:]> ---------
template<int HEADS, int CH>
__global__ __launch_bounds__(256) void scores_kernel(const __half* __restrict__ Hf,
                                                     const float* __restrict__ as_,
                                                     const float* __restrict__ ad_,
                                                     float* __restrict__ ssrc,
                                                     float* __restrict__ sdst, int n) {
  int t = blockIdx.x * blockDim.x + threadIdx.x;
  if (t >= n * HEADS) return;
  int hd = t % HEADS;
  const __half2* hp2 = reinterpret_cast<const __half2*>(Hf + (size_t)t * CH);
  float a = 0.f, b = 0.f;
  #pragma unroll
  for (int c2 = 0; c2 < CH / 2; ++c2) {
    float2 v = __half22float2(hp2[c2]);
    a += v.x * as_[hd * CH + 2 * c2] + v.y * as_[hd * CH + 2 * c2 + 1];
    b += v.x * ad_[hd * CH + 2 * c2] + v.y * ad_[hd * CH + 2 * c2 + 1];
  }
  ssrc[t] = a; sdst[t] = b;
}

// ---------------- CSR build: histogram of dst ----------------
__global__ __launch_bounds__(256) void hist_kernel(const int* __restrict__ ei, int E,
                                                   int* __restrict__ deg) {
  int e = blockIdx.x * blockDim.x + threadIdx.x;
  if (e >= E) return;
  atomicAdd(&deg[ei[E + e]], 1);
}

// ---------------- parallel scan, step 1: per-block (1024-chunk) sums ----------------
__global__ __launch_bounds__(256) void scan_blocksums(const int* __restrict__ deg,
                                                      int* __restrict__ bsum, int N) {
  __shared__ int red[256];
  int base = blockIdx.x * 1024 + threadIdx.x * 4;
  int s = 0;
  #pragma unroll
  for (int i = 0; i < 4; ++i) { int idx = base + i; if (idx < N) s += deg[idx]; }
  red[threadIdx.x] = s;
  __syncthreads();
  for (int off = 128; off > 0; off >>= 1) {
    if (threadIdx.x < off) red[threadIdx.x] += red[threadIdx.x + off];
    __syncthreads();
  }
  if (threadIdx.x == 0) bsum[blockIdx.x] = red[0];
}

// ---------------- parallel scan, step 2: exclusive scan of block sums (nb <= 1024) ----------------
__global__ __launch_bounds__(1024) void scan_bsum(int* __restrict__ bsum, int nb) {
  __shared__ int sh[1024];
  int t = threadIdx.x;
  int v = (t < nb) ? bsum[t] : 0;
  sh[t] = v;
  __syncthreads();
  for (int off = 1; off < 1024; off <<= 1) {
    int tmp = (t >= off) ? sh[t - off] : 0;
    __syncthreads();
    sh[t] += tmp;
    __syncthreads();
  }
  if (t < nb) bsum[t] = sh[t] - v;   // exclusive
}

// ---------------- parallel scan, step 3: per-block rescan + offset, emit rowptr/cursor ----------------
__global__ __launch_bounds__(256) void scan_final(const int* __restrict__ deg,
                                                  const int* __restrict__ bsum,
                                                  int* __restrict__ rowptr,
                                                  int* __restrict__ cursor, int N) {
  __shared__ int sh[256];
  const int t = threadIdx.x;
  const int base = blockIdx.x * 1024 + t * 4;
  int d[4] = {0, 0, 0, 0};
  #pragma unroll
  for (int i = 0; i < 4; ++i) if (base + i < N) d[i] = deg[base + i];
  int s = d[0] + d[1] + d[2] + d[3];
  sh[t] = s;
  __syncthreads();
  for (int off = 1; off < 256; off <<= 1) {
    int tmp = (t >= off) ? sh[t - off] : 0;
    __syncthreads();
    sh[t] += tmp;
    __syncthreads();
  }
  int run = bsum[blockIdx.x] + sh[t] - s;   // exclusive prefix for this thread
  #pragma unroll
  for (int i = 0; i < 4; ++i) {
    if (base + i < N) { rowptr[base + i] = run; cursor[base + i] = run; run += d[i]; }
  }
  if (blockIdx.x == gridDim.x - 1 && t == 255) rowptr[N] = run;   // total (= E)
}

// ---------------- CSR scatter, range-split: pass p handles dst in [p*PW, (p+1)*PW) ----------------
// keeps the active col region ~L2-resident so 64B lines fill before eviction
__global__ __launch_bounds__(256) void scatter_pass(const int* __restrict__ ei, int E, int N,
                                                    int pw,
                                                    int* __restrict__ cursor,
                                                    int* __restrict__ col) {
  int e = blockIdx.x * blockDim.x + threadIdx.x;
  if (e >= E) return;
  int lo = blockIdx.y * pw;
  int hi = lo + pw;
  int d = ei[E + e];
  if (d < lo || d >= hi) return;
  int pos = atomicAdd(&cursor[d], 1);
  col[pos] = ei[e];
}

// --------- softmax alphas: wave per node, lanes parallel over (edge-slot, head) ---------
template<int HEADS>
__global__ __launch_bounds__(256) void alpha_kernel(
    const int* __restrict__ rowptr, const int* __restrict__ col,
    const float* __restrict__ ssrc, const float* __restrict__ sdst,
    __half* __restrict__ alpha, float* __restrict__ aself,
    float* __restrict__ sinv, int N) {
  constexpr int SLOTS = 64 / HEADS;
  const int wid = blockIdx.x * 4 + (threadIdx.x >> 6);
  if (wid >= N) return;
  const int lane = threadIdx.x & 63;
  const int eslot = lane / HEADS;
  const int head = lane & (HEADS - 1);
  const int n = wid;
  const float sd = sdst[n * HEADS + head];
  const int beg = rowptr[n], end = rowptr[n + 1];

  float lgs = ssrc[n * HEADS + head] + sd;           // self-loop logit
  lgs = lgs > 0.f ? lgs : 0.2f * lgs;
  float m = lgs;
  for (int base = beg; base < end; base += SLOTS) {
    int e = base + eslot;
    if (e < end) {
      int src = col[e];
      float lg = ssrc[src * HEADS + head] + sd;
      lg = lg > 0.f ? lg : 0.2f * lg;
      m = fmaxf(m, lg);
    }
  }
  #pragma unroll
  for (int off = HEADS; off < 64; off <<= 1) m = fmaxf(m, __shfl_xor(m, off));

  float s = 0.f;
  for (int base = beg; base < end; base += SLOTS) {
    int e = base + eslot;
    if (e < end) {
      int src = col[e];
      float lg = ssrc[src * HEADS + head] + sd;
      lg = lg > 0.f ? lg : 0.2f * lg;
      float p = __expf(lg - m);
      alpha[(size_t)e * HEADS + head] = __float2half_rn(p);
      s += p;
    }
  }
  #pragma unroll
  for (int off = HEADS; off < 64; off <<= 1) s += __shfl_xor(s, off);
  float ps = __expf(lgs - m);
  s += ps;
  if (eslot == 0) {
    aself[n * HEADS + head] = ps;
    sinv[n * HEADS + head] = 1.f / s;
  }
}

// --------- aggregation: pure gather-FMA, wave per node, deferred normalization ---------
template<int HEADS, int CH, int VEC, bool BN, bool OUTH>   // NOUT = HEADS*CH; VEC = NOUT/64
__global__ __launch_bounds__(256) void aggr2_kernel(
    const int* __restrict__ rowptr, const int* __restrict__ col,
    const __half* __restrict__ Hf,
    const __half* __restrict__ alpha, const float* __restrict__ aself,
    const float* __restrict__ sinv,
    const float* __restrict__ bias, const float* __restrict__ g,
    const float* __restrict__ be, const float* __restrict__ rm,
    const float* __restrict__ rv,
    void* __restrict__ outp, int N) {
  constexpr int NOUT = HEADS * CH;
  const int wid = blockIdx.x * 4 + (threadIdx.x >> 6);
  const int lane = threadIdx.x & 63;
  if (wid >= N) return;
  const int n = wid;
  const int c0 = lane * VEC;
  const int head = c0 / CH;

  float a0, a1 = 0.f;
  {
    float asf = aself[n * HEADS + head];
    if (VEC == 2) {
      float2 hf = __half22float2(*reinterpret_cast<const __half2*>(&Hf[(size_t)n * NOUT + c0]));
      a0 = asf * hf.x; a1 = asf * hf.y;
    } else {
      a0 = asf * __half2float(Hf[(size_t)n * NOUT + c0]);
    }
  }

  const int beg = rowptr[n], end = rowptr[n + 1];
  #pragma unroll 4
  for (int e = beg; e < end; ++e) {
    int src = col[e];
    float al = __half2float(alpha[(size_t)e * HEADS + head]);
    if (VEC == 2) {
      float2 hf = __half22float2(*reinterpret_cast<const __half2*>(&Hf[(size_t)src * NOUT + c0]));
      a0 += al * hf.x;
      a1 += al * hf.y;
    } else {
      a0 += al * __half2float(Hf[(size_t)src * NOUT + c0]);
    }
  }

  const float inv = sinv[n * HEADS + head];
  float o0 = a0 * inv + bias[c0];
  if (BN) {
    o0 = (o0 - rm[c0]) * rsqrtf(rv[c0] + 1e-5f) * g[c0] + be[c0];
    o0 = o0 > 0.f ? o0 : expm1f(o0);
  }
  if (VEC == 2) {
    float o1 = a1 * inv + bias[c0 + 1];
    if (BN) {
      o1 = (o1 - rm[c0 + 1]) * rsqrtf(rv[c0 + 1] + 1e-5f) * g[c0 + 1] + be[c0 + 1];
      o1 = o1 > 0.f ? o1 : expm1f(o1);
    }
    if (OUTH) {
      __half2 o = __floats2half2_rn(o0, o1);
      *reinterpret_cast<__half2*>(&((__half*)outp)[(size_t)n * NOUT + c0]) = o;
    } else {
      float2 o = make_float2(o0, o1);
      *reinterpret_cast<float2*>(&((float*)outp)[(size_t)n * NOUT + c0]) = o;
    }
  } else {
    if (OUTH) ((__half*)outp)[(size_t)n * NOUT + c0] = __float2half_rn(o0);
    else      ((float*)outp)[(size_t)n * NOUT + c0] = o0;
  }
}

extern "C" void kernel_launch(void* const* d_in, const int* in_sizes, int n_in,
                              void* d_out, int out_size, void* d_ws, size_t ws_size,
                              hipStream_t stream) {
  const float* x   = (const float*)d_in[0];
  const int*   ei  = (const int*)d_in[1];
  const float* W1  = (const float*)d_in[2];
  const float* as1 = (const float*)d_in[3];
  const float* ad1 = (const float*)d_in[4];
  const float* b1  = (const float*)d_in[5];
  const float* g1  = (const float*)d_in[6];
  const float* be1 = (const float*)d_in[7];
  const float* rm1 = (const float*)d_in[8];
  const float* rv1 = (const float*)d_in[9];
  const float* W2  = (const float*)d_in[10];
  const float* as2 = (const float*)d_in[11];
  const float* ad2 = (const float*)d_in[12];
  const float* b2  = (const float*)d_in[13];
  const float* g2  = (const float*)d_in[14];
  const float* be2 = (const float*)d_in[15];
  const float* rm2 = (const float*)d_in[16];
  const float* rv2 = (const float*)d_in[17];
  const float* W3  = (const float*)d_in[18];
  const float* as3 = (const float*)d_in[19];
  const float* ad3 = (const float*)d_in[20];
  const float* b3  = (const float*)d_in[21];

  const int N = in_sizes[0] / 128;
  const int E = in_sizes[1] / 2;
  float* out = (float*)d_out;

  // workspace layout (bytes)
  char* p = (char*)d_ws;
  __half* Ah  = (__half*)p;  p += (size_t)N * 128 * 2;   // h buffer (GEMM out)
  __half* Bh  = (__half*)p;  p += (size_t)N * 128 * 2;   // layer in/out (fp16); holds xh first
  float* ssrc = (float*)p;   p += (size_t)N * 4 * 4;
  float* sdst = (float*)p;   p += (size_t)N * 4 * 4;
  float* aself= (float*)p;   p += (size_t)N * 4 * 4;
  float* sinv = (float*)p;   p += (size_t)N * 4 * 4;
  __half* alpha=(__half*)p;  p += (size_t)E * 4 * 2;
  int* deg    = (int*)p;     p += (size_t)N * 4;
  int* rowptr = (int*)p;     p += (size_t)(N + 1) * 4;
  int* cursor = (int*)p;     p += (size_t)N * 4;
  int* col    = (int*)p;     p += (size_t)E * 4;
  int* bsum   = (int*)p;

  const int aggrB = CDIV(N, 4);                  // one wave per node, 4 waves/block
  const int nb = CDIV(N, 1024);                  // scan blocks
  const int gemmB = CDIV(N, 64);                 // 4 row-tiles (16 rows) per block
  constexpr int NPASS = 8;
  const int pw = CDIV(N, NPASS);

  // ---------------- CSR build (by dst), reused by all 3 layers ----------------
  hipMemsetAsync(deg, 0, (size_t)N * sizeof(int), stream);
  hist_kernel<<<CDIV(E, 256), 256, 0, stream>>>(ei, E, deg);
  scan_blocksums<<<nb, 256, 0, stream>>>(deg, bsum, N);
  scan_bsum<<<1, 1024, 0, stream>>>(bsum, nb);
  scan_final<<<nb, 256, 0, stream>>>(deg, bsum, rowptr, cursor, N);
  scatter_pass<<<dim3(CDIV(E, 256), NPASS), 256, 0, stream>>>(ei, E, N, pw, cursor, col);

  // x -> fp16 (into Bh; consumed by layer-1 GEMM before Bh is overwritten)
  conv_kernel<<<CDIV(N * 128 / 4, 256), 256, 0, stream>>>(x, Bh, N * 128 / 4);

  // ---------------- layer 1: GAT(128 -> 4x32) + BN + ELU ----------------
  gemm_mfma<128><<<gemmB, 256, 0, stream>>>(Bh, W1, Ah, N);
  scores_kernel<4, 32><<<CDIV(N * 4, 256), 256, 0, stream>>>(Ah, as1, ad1, ssrc, sdst, N);
  alpha_kernel<4><<<aggrB, 256, 0, stream>>>(rowptr, col, ssrc, sdst, alpha, aself, sinv, N);
  aggr2_kernel<4, 32, 2, true, true><<<aggrB, 256, 0, stream>>>(rowptr, col, Ah, alpha, aself, sinv,
                                                                b1, g1, be1, rm1, rv1, Bh, N);

  // ---------------- layer 2: GAT(128 -> 4x32) + BN + ELU ----------------
  gemm_mfma<128><<<gemmB, 256, 0, stream>>>(Bh, W2, Ah, N);
  scores_kernel<4, 32><<<CDIV(N * 4, 256), 256, 0, stream>>>(Ah, as2, ad2, ssrc, sdst, N);
  alpha_kernel<4><<<aggrB, 256, 0, stream>>>(rowptr, col, ssrc, sdst, alpha, aself, sinv, N);
  aggr2_kernel<4, 32, 2, true, true><<<aggrB, 256, 0, stream>>>(rowptr, col, Ah, alpha, aself, sinv,
                                                                b2, g2, be2, rm2, rv2, Bh, N);

  // ---------------- layer 3: GAT(128 -> 64, heads=1, no BN), fp32 out ----------------
  gemm_mfma<64><<<gemmB, 256, 0, stream>>>(Bh, W3, Ah, N);
  scores_kernel<1, 64><<<CDIV(N, 256), 256, 0, stream>>>(Ah, as3, ad3, ssrc, sdst, N);
  alpha_kernel<1><<<aggrB, 256, 0, stream>>>(rowptr, col, ssrc, sdst, alpha, aself, sinv, N);
  aggr2_kernel<1, 64, 1, false, false><<<aggrB, 256, 0, stream>>>(rowptr, col, Ah, alpha, aself, sinv,
                                                                  b3, b3, b3, b3, b3, out, N);
}

// Round 7
// 489.822 us; speedup vs baseline: 9.9604x; 1.2302x over previous
//
#include <hip/hip_runtime.h>
#include <hip/hip_fp16.h>

#define CDIV(a,b) (((a)+(b)-1)/(b))

typedef _Float16 f16x8 __attribute__((ext_vector_type(8)));
typedef float f32x4 __attribute__((ext_vector_type(4)));

// ---------------- fp32 -> fp16 convert (x input, once per launch) ----------------
__global__ __launch_bounds__(256) void conv_kernel(const float* __restrict__ X,
                                                   __half* __restrict__ Y, int total4) {
  int t = blockIdx.x * blockDim.x + threadIdx.x;
  if (t >= total4) return;
  float4 v = reinterpret_cast<const float4*>(X)[t];
  __half2 a = __floats2half2_rn(v.x, v.y);
  __half2 b = __floats2half2_rn(v.z, v.w);
  reinterpret_cast<__half2*>(Y)[t * 2]     = a;
  reinterpret_cast<__half2*>(Y)[t * 2 + 1] = b;
}

// ---------------- W prep: fp32 row-major -> fp16 fragment-major ----------------
// element (k,c), k = s*32 + g*8 + i  ->  Wt[((s*4+g)*NOUT + c)*8 + i]
__global__ __launch_bounds__(256) void wprep_kernel(const float* __restrict__ W,
                                                    _Float16* __restrict__ Wt, int NOUT) {
  int i = blockIdx.x * blockDim.x + threadIdx.x;
  if (i >= 128 * NOUT) return;
  int k = i / NOUT, c = i % NOUT;
  int s = k >> 5, g = (k >> 3) & 3, e = k & 7;
  Wt[(size_t)((s * 4 + g) * NOUT + c) * 8 + e] = (_Float16)W[i];
}

// ---------------- MFMA GEMM: Y[n,NOUT](fp16) = X[n,128](fp16) @ Wt (frag-major fp16) ----------------
// one wave per 16-row tile; B-fragments straight from global (L2-resident), no LDS
template<int NOUT>
__global__ __launch_bounds__(256) void gemm_mfma(const __half* __restrict__ Xh,
                                                 const _Float16* __restrict__ Wt,
                                                 __half* __restrict__ Y, int nrows) {
  constexpr int K = 128;
  constexpr int CT = NOUT / 16;      // col tiles
  const int wave = threadIdx.x >> 6, lane = threadIdx.x & 63;
  const int g = lane >> 4, r16 = lane & 15;
  const int rt = blockIdx.x * 4 + wave;
  if (rt * 16 >= nrows) return;

  // A fragments: row = lane&15, k = s*32 + g*8 + i (same k-bijection as B)
  const _Float16* xrow = reinterpret_cast<const _Float16*>(Xh)
                         + (size_t)(rt * 16 + r16) * K + g * 8;
  f16x8 a[4];
  #pragma unroll
  for (int s = 0; s < 4; ++s) a[s] = *reinterpret_cast<const f16x8*>(xrow + s * 32);

  f32x4 acc[CT];
  #pragma unroll
  for (int ct = 0; ct < CT; ++ct) acc[ct] = (f32x4){0.f, 0.f, 0.f, 0.f};

  #pragma unroll
  for (int ct = 0; ct < CT; ++ct) {
    #pragma unroll
    for (int s = 0; s < 4; ++s) {
      f16x8 b = *reinterpret_cast<const f16x8*>(&Wt[(size_t)((s * 4 + g) * NOUT + ct * 16 + r16) * 8]);
      acc[ct] = __builtin_amdgcn_mfma_f32_16x16x32_f16(a[s], b, acc[ct], 0, 0, 0);
    }
  }
  // C/D: col = lane&15, row = (lane>>4)*4 + reg
  const int row0 = rt * 16 + g * 4;
  #pragma unroll
  for (int ct = 0; ct < CT; ++ct) {
    #pragma unroll
    for (int r = 0; r < 4; ++r) {
      Y[(size_t)(row0 + r) * NOUT + ct * 16 + r16] = __float2half_rn(acc[ct][r]);
    }
  }
}

// --------- per-node attention scores: s_src/s_dst[n,h] = <h[n,h,:], a_{s,d}[h,:]> ---------
template<int HEADS, int CH>
__global__ __launch_bounds__(256) void scores_kernel(const __half* __restrict__ Hf,
                                                     const float* __restrict__ as_,
                                                     const float* __restrict__ ad_,
                                                     float* __restrict__ ssrc,
                                                     float* __restrict__ sdst, int n) {
  int t = blockIdx.x * blockDim.x + threadIdx.x;
  if (t >= n * HEADS) return;
  int hd = t % HEADS;
  const __half2* hp2 = reinterpret_cast<const __half2*>(Hf + (size_t)t * CH);
  float a = 0.f, b = 0.f;
  #pragma unroll
  for (int c2 = 0; c2 < CH / 2; ++c2) {
    float2 v = __half22float2(hp2[c2]);
    a += v.x * as_[hd * CH + 2 * c2] + v.y * as_[hd * CH + 2 * c2 + 1];
    b += v.x * ad_[hd * CH + 2 * c2] + v.y * ad_[hd * CH + 2 * c2 + 1];
  }
  ssrc[t] = a; sdst[t] = b;
}

// ---------------- CSR build: histogram of dst ----------------
__global__ __launch_bounds__(256) void hist_kernel(const int* __restrict__ ei, int E,
                                                   int* __restrict__ deg) {
  int e = blockIdx.x * blockDim.x + threadIdx.x;
  if (e >= E) return;
  atomicAdd(&deg[ei[E + e]], 1);
}

// ---------------- parallel scan, step 1: per-block (1024-chunk) sums ----------------
__global__ __launch_bounds__(256) void scan_blocksums(const int* __restrict__ deg,
                                                      int* __restrict__ bsum, int N) {
  __shared__ int red[256];
  int base = blockIdx.x * 1024 + threadIdx.x * 4;
  int s = 0;
  #pragma unroll
  for (int i = 0; i < 4; ++i) { int idx = base + i; if (idx < N) s += deg[idx]; }
  red[threadIdx.x] = s;
  __syncthreads();
  for (int off = 128; off > 0; off >>= 1) {
    if (threadIdx.x < off) red[threadIdx.x] += red[threadIdx.x + off];
    __syncthreads();
  }
  if (threadIdx.x == 0) bsum[blockIdx.x] = red[0];
}

// ---------------- parallel scan, step 2: exclusive scan of block sums (nb <= 1024) ----------------
__global__ __launch_bounds__(1024) void scan_bsum(int* __restrict__ bsum, int nb) {
  __shared__ int sh[1024];
  int t = threadIdx.x;
  int v = (t < nb) ? bsum[t] : 0;
  sh[t] = v;
  __syncthreads();
  for (int off = 1; off < 1024; off <<= 1) {
    int tmp = (t >= off) ? sh[t - off] : 0;
    __syncthreads();
    sh[t] += tmp;
    __syncthreads();
  }
  if (t < nb) bsum[t] = sh[t] - v;   // exclusive
}

// ---------------- parallel scan, step 3: per-block rescan + offset, emit rowptr/cursor ----------------
__global__ __launch_bounds__(256) void scan_final(const int* __restrict__ deg,
                                                  const int* __restrict__ bsum,
                                                  int* __restrict__ rowptr,
                                                  int* __restrict__ cursor, int N) {
  __shared__ int sh[256];
  const int t = threadIdx.x;
  const int base = blockIdx.x * 1024 + t * 4;
  int d[4] = {0, 0, 0, 0};
  #pragma unroll
  for (int i = 0; i < 4; ++i) if (base + i < N) d[i] = deg[base + i];
  int s = d[0] + d[1] + d[2] + d[3];
  sh[t] = s;
  __syncthreads();
  for (int off = 1; off < 256; off <<= 1) {
    int tmp = (t >= off) ? sh[t - off] : 0;
    __syncthreads();
    sh[t] += tmp;
    __syncthreads();
  }
  int run = bsum[blockIdx.x] + sh[t] - s;   // exclusive prefix for this thread
  #pragma unroll
  for (int i = 0; i < 4; ++i) {
    if (base + i < N) { rowptr[base + i] = run; cursor[base + i] = run; run += d[i]; }
  }
  if (blockIdx.x == gridDim.x - 1 && t == 255) rowptr[N] = run;   // total (= E)
}

// ---------------- CSR scatter, range-split over dst to keep col region L2-resident ----------------
__global__ __launch_bounds__(256) void scatter_pass(const int* __restrict__ ei, int E, int N,
                                                    int pw,
                                                    int* __restrict__ cursor,
                                                    int* __restrict__ col) {
  int e = blockIdx.x * blockDim.x + threadIdx.x;
  if (e >= E) return;
  int lo = blockIdx.y * pw;
  int hi = lo + pw;
  int d = ei[E + e];
  if (d < lo || d >= hi) return;
  int pos = atomicAdd(&cursor[d], 1);
  col[pos] = ei[e];
}

// --------- FUSED softmax + aggregation: one wave per node, one edge pass ---------
// stabilizer K = self logit (leaky_relu monotone + softmax shift-invariance => exact)
template<int HEADS, int CH, bool BN, bool OUTH>
__global__ __launch_bounds__(256) void gat_fused(
    const int* __restrict__ rowptr, const int* __restrict__ col,
    const __half* __restrict__ Hf,
    const float* __restrict__ ssrc, const float* __restrict__ sdst,
    const float* __restrict__ bias, const float* __restrict__ g,
    const float* __restrict__ be, const float* __restrict__ rm,
    const float* __restrict__ rv,
    void* __restrict__ outp, int N) {
  constexpr int NOUT = HEADS * CH;
  constexpr int VEC = NOUT / 64;       // 2 (128ch) or 1 (64ch)
  constexpr int SLOTS = 64 / HEADS;    // edges per tile
  __shared__ float ptile[4][SLOTS][HEADS];
  __shared__ int   stile[4][SLOTS];
  const int wv = threadIdx.x >> 6, lane = threadIdx.x & 63;
  const int n = blockIdx.x * 4 + wv;
  if (n >= N) return;
  const int eslot = lane / HEADS, head = lane & (HEADS - 1);
  const float sd = sdst[n * HEADS + head];
  float lgs = ssrc[n * HEADS + head] + sd;       // self logit = stabilizer K
  lgs = lgs > 0.f ? lgs : 0.2f * lgs;

  // phase-B channel mapping
  const int c0 = lane * VEC;
  const int hb = c0 / CH;

  // self contribution: p_self = exp(lgs - K) = 1
  float a0, a1 = 0.f;
  if (VEC == 2) {
    float2 hf = __half22float2(*reinterpret_cast<const __half2*>(&Hf[(size_t)n * NOUT + c0]));
    a0 = hf.x; a1 = hf.y;
  } else {
    a0 = __half2float(Hf[(size_t)n * NOUT + c0]);
  }

  float s = 0.f;                                  // sum of p over real edges
  const int beg = rowptr[n], end = rowptr[n + 1];
  for (int base = beg; base < end; base += SLOTS) {
    // phase A: lanes over (edge-slot, head) -> p into LDS
    int e = base + eslot;
    float p = 0.f; int src = 0;
    if (e < end) {
      src = col[e];
      float lg = ssrc[src * HEADS + head] + sd;
      lg = lg > 0.f ? lg : 0.2f * lg;
      p = __expf(lg - lgs);
    }
    ptile[wv][eslot][head] = p;                  // p=0 pads tail slots
    if (head == 0) stile[wv][eslot] = src;
    s += p;
    asm volatile("s_waitcnt lgkmcnt(0)" ::: "memory");   // wave-local LDS visibility

    // phase B: lanes over channels, gather-FMA
    int cnt = min(SLOTS, end - base);
    if (cnt == SLOTS) {
      #pragma unroll 16
      for (int j = 0; j < SLOTS; ++j) {
        int sj = stile[wv][j];
        float pj = ptile[wv][j][hb];
        if (VEC == 2) {
          float2 hf = __half22float2(*reinterpret_cast<const __half2*>(&Hf[(size_t)sj * NOUT + c0]));
          a0 += pj * hf.x; a1 += pj * hf.y;
        } else {
          a0 += pj * __half2float(Hf[(size_t)sj * NOUT + c0]);
        }
      }
    } else {
      for (int j = 0; j < cnt; ++j) {
        int sj = stile[wv][j];
        float pj = ptile[wv][j][hb];
        if (VEC == 2) {
          float2 hf = __half22float2(*reinterpret_cast<const __half2*>(&Hf[(size_t)sj * NOUT + c0]));
          a0 += pj * hf.x; a1 += pj * hf.y;
        } else {
          a0 += pj * __half2float(Hf[(size_t)sj * NOUT + c0]);
        }
      }
    }
  }

  // denominator: reduce p-sums across edge-slots (per head), add self
  #pragma unroll
  for (int off = HEADS; off < 64; off <<= 1) s += __shfl_xor(s, off);
  float inv = 1.f / (s + 1.f);                    // lane's value valid for head = lane&(H-1)
  float invb = __shfl(inv, hb);                   // lane hb holds head hb

  float o0 = a0 * invb + bias[c0];
  if (BN) {
    o0 = (o0 - rm[c0]) * rsqrtf(rv[c0] + 1e-5f) * g[c0] + be[c0];
    o0 = o0 > 0.f ? o0 : expm1f(o0);
  }
  if (VEC == 2) {
    float o1 = a1 * invb + bias[c0 + 1];
    if (BN) {
      o1 = (o1 - rm[c0 + 1]) * rsqrtf(rv[c0 + 1] + 1e-5f) * g[c0 + 1] + be[c0 + 1];
      o1 = o1 > 0.f ? o1 : expm1f(o1);
    }
    if (OUTH) {
      __half2 o = __floats2half2_rn(o0, o1);
      *reinterpret_cast<__half2*>(&((__half*)outp)[(size_t)n * NOUT + c0]) = o;
    } else {
      float2 o = make_float2(o0, o1);
      *reinterpret_cast<float2*>(&((float*)outp)[(size_t)n * NOUT + c0]) = o;
    }
  } else {
    if (OUTH) ((__half*)outp)[(size_t)n * NOUT + c0] = __float2half_rn(o0);
    else      ((float*)outp)[(size_t)n * NOUT + c0] = o0;
  }
}

extern "C" void kernel_launch(void* const* d_in, const int* in_sizes, int n_in,
                              void* d_out, int out_size, void* d_ws, size_t ws_size,
                              hipStream_t stream) {
  const float* x   = (const float*)d_in[0];
  const int*   ei  = (const int*)d_in[1];
  const float* W1  = (const float*)d_in[2];
  const float* as1 = (const float*)d_in[3];
  const float* ad1 = (const float*)d_in[4];
  const float* b1  = (const float*)d_in[5];
  const float* g1  = (const float*)d_in[6];
  const float* be1 = (const float*)d_in[7];
  const float* rm1 = (const float*)d_in[8];
  const float* rv1 = (const float*)d_in[9];
  const float* W2  = (const float*)d_in[10];
  const float* as2 = (const float*)d_in[11];
  const float* ad2 = (const float*)d_in[12];
  const float* b2  = (const float*)d_in[13];
  const float* g2  = (const float*)d_in[14];
  const float* be2 = (const float*)d_in[15];
  const float* rm2 = (const float*)d_in[16];
  const float* rv2 = (const float*)d_in[17];
  const float* W3  = (const float*)d_in[18];
  const float* as3 = (const float*)d_in[19];
  const float* ad3 = (const float*)d_in[20];
  const float* b3  = (const float*)d_in[21];

  const int N = in_sizes[0] / 128;
  const int E = in_sizes[1] / 2;
  float* out = (float*)d_out;

  // workspace layout (bytes)
  char* p = (char*)d_ws;
  __half* Ah  = (__half*)p;  p += (size_t)N * 128 * 2;   // h buffer (GEMM out)
  __half* Bh  = (__half*)p;  p += (size_t)N * 128 * 2;   // layer in/out (fp16); holds xh first
  float* ssrc = (float*)p;   p += (size_t)N * 4 * 4;
  float* sdst = (float*)p;   p += (size_t)N * 4 * 4;
  int* deg    = (int*)p;     p += (size_t)N * 4;
  int* rowptr = (int*)p;     p += (size_t)(N + 1) * 4;
  int* cursor = (int*)p;     p += (size_t)N * 4;
  int* col    = (int*)p;     p += (size_t)E * 4;
  int* bsum   = (int*)p;     p += 4096;
  _Float16* Wt1 = (_Float16*)p; p += (size_t)128 * 128 * 2;
  _Float16* Wt2 = (_Float16*)p; p += (size_t)128 * 128 * 2;
  _Float16* Wt3 = (_Float16*)p;

  const int fusedB = CDIV(N, 4);                 // one wave per node, 4 waves/block
  const int nb = CDIV(N, 1024);                  // scan blocks
  const int gemmB = CDIV(N, 64);                 // 4 row-tiles (16 rows) per block
  constexpr int NPASS = 8;
  const int pw = CDIV(N, NPASS);

  // ---------------- CSR build (by dst), reused by all 3 layers ----------------
  hipMemsetAsync(deg, 0, (size_t)N * sizeof(int), stream);
  hist_kernel<<<CDIV(E, 256), 256, 0, stream>>>(ei, E, deg);
  scan_blocksums<<<nb, 256, 0, stream>>>(deg, bsum, N);
  scan_bsum<<<1, 1024, 0, stream>>>(bsum, nb);
  scan_final<<<nb, 256, 0, stream>>>(deg, bsum, rowptr, cursor, N);
  scatter_pass<<<dim3(CDIV(E, 256), NPASS), 256, 0, stream>>>(ei, E, N, pw, cursor, col);

  // W -> fragment-major fp16 (once), x -> fp16
  wprep_kernel<<<CDIV(128 * 128, 256), 256, 0, stream>>>(W1, Wt1, 128);
  wprep_kernel<<<CDIV(128 * 128, 256), 256, 0, stream>>>(W2, Wt2, 128);
  wprep_kernel<<<CDIV(128 * 64, 256), 256, 0, stream>>>(W3, Wt3, 64);
  conv_kernel<<<CDIV(N * 128 / 4, 256), 256, 0, stream>>>(x, Bh, N * 128 / 4);

  // ---------------- layer 1: GAT(128 -> 4x32) + BN + ELU ----------------
  gemm_mfma<128><<<gemmB, 256, 0, stream>>>(Bh, Wt1, Ah, N);
  scores_kernel<4, 32><<<CDIV(N * 4, 256), 256, 0, stream>>>(Ah, as1, ad1, ssrc, sdst, N);
  gat_fused<4, 32, true, true><<<fusedB, 256, 0, stream>>>(rowptr, col, Ah, ssrc, sdst,
                                                           b1, g1, be1, rm1, rv1, Bh, N);

  // ---------------- layer 2: GAT(128 -> 4x32) + BN + ELU ----------------
  gemm_mfma<128><<<gemmB, 256, 0, stream>>>(Bh, Wt2, Ah, N);
  scores_kernel<4, 32><<<CDIV(N * 4, 256), 256, 0, stream>>>(Ah, as2, ad2, ssrc, sdst, N);
  gat_fused<4, 32, true, true><<<fusedB, 256, 0, stream>>>(rowptr, col, Ah, ssrc, sdst,
                                                           b2, g2, be2, rm2, rv2, Bh, N);

  // ---------------- layer 3: GAT(128 -> 64, heads=1, no BN), fp32 out ----------------
  gemm_mfma<64><<<gemmB, 256, 0, stream>>>(Bh, Wt3, Ah, N);
  scores_kernel<1, 64><<<CDIV(N, 256), 256, 0, stream>>>(Ah, as3, ad3, ssrc, sdst, N);
  gat_fused<1, 64, false, false><<<fusedB, 256, 0, stream>>>(rowptr, col, Ah, ssrc, sdst,
                                                             b3, b3, b3, b3, b3, out, N);
}